// Round 4
// baseline (1334.185 us; speedup 1.0000x reference)
//
#include <hip/hip_runtime.h>
#include <math.h>

namespace {

typedef float f32x2 __attribute__((ext_vector_type(2)));

#if defined(__has_builtin)
#if __has_builtin(__builtin_elementwise_fma)
#define HAVE_EW_FMA 1
#endif
#endif

__device__ __forceinline__ f32x2 pkfma(f32x2 a, f32x2 b, f32x2 c) {
#ifdef HAVE_EW_FMA
  return __builtin_elementwise_fma(a, b, c);
#else
  return a * b + c;   // -ffp-contract=fast fuses per element
#endif
}

constexpr int IMS  = 84;
constexpr int NPIX = IMS * IMS;      // 7056
constexpr int KOBJ = 20;

// ---- workspace layout (float offsets), peak = 27448320 floats = 110 MB ----
constexpr size_t OFF_X    = 0;            // 512*512            -> 262144
constexpr size_t OFF_OT   = 262144;       // 512*40             -> 282624
constexpr size_t OFF_CT   = 282624;       // 512*2 (pad)        -> 283648
constexpr size_t OFF_WT2  = 283648;       // 512*64             -> 316416
constexpr size_t OFF_WT3  = 316416;       // 576*64             -> 353280
constexpr size_t OFF_M0   = 353280;       // 512*10584          -> 5772288
constexpr size_t OFF_R1   = 5772288;      // 512*24*42*42       -> 27448320
// H1/H2/FEAT alias into the R1 region (dead before upconv1 writes R1)
constexpr size_t OFF_H1   = OFF_R1;       // 512*32*400         -> 12325888
constexpr size_t OFF_H2   = 12325888;     // 512*64*81          -> 14980096
constexpr size_t OFF_FEAT = 14980096;     // 512*3136           -> 16585728
// decoder conv weights (transposed, 5184 floats each) reuse WT2/WT3 slots
// after conv2/conv3 are done with them.

// ---- generic weight transpose: w[oc][ckk] -> wt[ckk][oc] ----
__global__ void transpose_w(const float* __restrict__ w, float* __restrict__ wt,
                            int OC, int CKK) {
  int idx = blockIdx.x * 256 + threadIdx.x;
  if (idx < OC * CKK) {
    int oc = idx / CKK, ckk = idx % CKK;
    wt[ckk * OC + oc] = w[idx];
  }
}

// ---- decoder conv weight transpose: w[oc][ic][ky][kx] -> wt[tap][ic][oc] ----
__global__ void transpose_dec(const float* __restrict__ w, float* __restrict__ wt) {
  int idx = blockIdx.x * 256 + threadIdx.x;   // 24*24*9 = 5184
  if (idx < 5184) {
    int oc = idx / 216, rem = idx % 216, ic = rem / 9, tap = rem % 9;
    wt[(tap * 24 + ic) * 24 + oc] = w[idx];
  }
}

// ---- conv1: [B,2,84,84] -> [B,32,20,20], k=8 s=4, relu. LDS 44.6 KB ----
__global__ __launch_bounds__(256) void conv1_k(
    const float* __restrict__ inp, const float* __restrict__ w,
    const float* __restrict__ bias, float* __restrict__ out) {
  __shared__ __align__(16) float sIn[NPIX];      // one channel at a time
  __shared__ __align__(16) float sW[128 * 32];   // [c][u][v][oc]
  const int b = blockIdx.x, t = threadIdx.x;
  for (int i = t; i < 4096; i += 256) {
    int oc = i >> 7, ckk = i & 127;
    sW[ckk * 32 + oc] = w[i];
  }
  const float* ip = inp + (size_t)b * 2 * NPIX;
  const int oc0 = (t & 7) * 4;
  const int pg  = t >> 3;
  int ibase[13];
#pragma unroll
  for (int k = 0; k < 13; k++) {
    int p = pg + 32 * k; if (p > 399) p = 399;
    ibase[k] = (p / 20) * 4 * 84 + (p % 20) * 4;
  }
  f32x2 acc[13][2];
#pragma unroll
  for (int k = 0; k < 13; k++) { acc[k][0] = f32x2{0.f, 0.f}; acc[k][1] = f32x2{0.f, 0.f}; }
  for (int c = 0; c < 2; c++) {
    __syncthreads();
    for (int i = t; i < NPIX; i += 256) sIn[i] = ip[c * NPIX + i];
    __syncthreads();
    for (int u = 0; u < 8; u++) {
#pragma unroll
      for (int v = 0; v < 8; v++) {
        const float4 wv = *(const float4*)&sW[((c * 8 + u) * 8 + v) * 32 + oc0];
        const f32x2 w0 = {wv.x, wv.y}, w1 = {wv.z, wv.w};
        const int off = u * 84 + v;
#pragma unroll
        for (int k = 0; k < 13; k++) {
          float x = sIn[off + ibase[k]];
          f32x2 xv = {x, x};
          acc[k][0] = pkfma(w0, xv, acc[k][0]);
          acc[k][1] = pkfma(w1, xv, acc[k][1]);
        }
      }
    }
  }
  float b0 = bias[oc0], b1 = bias[oc0+1], b2 = bias[oc0+2], b3 = bias[oc0+3];
  float* op = out + (size_t)b * 32 * 400;
#pragma unroll
  for (int k = 0; k < 13; k++) {
    int p = pg + 32 * k;
    if (p < 400) {
      op[(oc0+0)*400 + p] = fmaxf(acc[k][0][0] + b0, 0.f);
      op[(oc0+1)*400 + p] = fmaxf(acc[k][0][1] + b1, 0.f);
      op[(oc0+2)*400 + p] = fmaxf(acc[k][1][0] + b2, 0.f);
      op[(oc0+3)*400 + p] = fmaxf(acc[k][1][1] + b3, 0.f);
    }
  }
}

// ---- conv2: [B,32,20,20] -> [B,64,9,9], k=4 s=2, relu. LDS 51.2 KB ----
__global__ __launch_bounds__(256) void conv2_k(
    const float* __restrict__ in, const float* __restrict__ wt,
    const float* __restrict__ bias, float* __restrict__ out) {
  __shared__ float sIn[32 * 400];
  const int b = blockIdx.x, t = threadIdx.x;
  const float* ip = in + (size_t)b * 12800;
  for (int i = t; i < 12800; i += 256) sIn[i] = ip[i];
  __syncthreads();
  const int oc0 = (t & 7) * 8;
  const int pg  = t >> 3;
  int base[3];
#pragma unroll
  for (int k = 0; k < 3; k++) {
    int p = pg + 32 * k; if (p > 80) p = 80;
    base[k] = (p / 9) * 40 + (p % 9) * 2;
  }
  f32x2 acc[3][4];
#pragma unroll
  for (int k = 0; k < 3; k++)
#pragma unroll
    for (int o = 0; o < 4; o++) acc[k][o] = f32x2{0.f, 0.f};
  for (int c = 0; c < 32; c++) {
#pragma unroll
    for (int u = 0; u < 4; u++)
#pragma unroll
      for (int v = 0; v < 4; v++) {
        const float* wp = wt + ((c * 4 + u) * 4 + v) * 64 + oc0;
        float4 wa = *(const float4*)wp;
        float4 wb = *(const float4*)(wp + 4);
        const f32x2 w0 = {wa.x, wa.y}, w1 = {wa.z, wa.w};
        const f32x2 w2 = {wb.x, wb.y}, w3 = {wb.z, wb.w};
        int off = c * 400 + u * 20 + v;
#pragma unroll
        for (int k = 0; k < 3; k++) {
          float x = sIn[off + base[k]];
          f32x2 xv = {x, x};
          acc[k][0] = pkfma(w0, xv, acc[k][0]);
          acc[k][1] = pkfma(w1, xv, acc[k][1]);
          acc[k][2] = pkfma(w2, xv, acc[k][2]);
          acc[k][3] = pkfma(w3, xv, acc[k][3]);
        }
      }
  }
  float* op = out + (size_t)b * 5184;
#pragma unroll
  for (int k = 0; k < 3; k++) {
    int p = pg + 32 * k;
    if (p < 81) {
#pragma unroll
      for (int o = 0; o < 8; o++)
        op[(oc0+o)*81 + p] = fmaxf(acc[k][o >> 1][o & 1] + bias[oc0+o], 0.f);
    }
  }
}

// ---- conv3: [B,64,9,9] -> feat [B,3136] (= [64][7][7] flat), k=3 s=1, relu ----
__global__ __launch_bounds__(256) void conv3_k(
    const float* __restrict__ in, const float* __restrict__ wt,
    const float* __restrict__ bias, float* __restrict__ out) {
  __shared__ float sIn[64 * 81];
  const int b = blockIdx.x, t = threadIdx.x;
  const float* ip = in + (size_t)b * 5184;
  for (int i = t; i < 5184; i += 256) sIn[i] = ip[i];
  __syncthreads();
  const int oc0 = (t & 7) * 8;
  const int pg  = t >> 3;
  int base[2];
#pragma unroll
  for (int k = 0; k < 2; k++) {
    int p = pg + 32 * k; if (p > 48) p = 48;
    base[k] = (p / 7) * 9 + (p % 7);
  }
  f32x2 acc[2][4];
#pragma unroll
  for (int k = 0; k < 2; k++)
#pragma unroll
    for (int o = 0; o < 4; o++) acc[k][o] = f32x2{0.f, 0.f};
  for (int c = 0; c < 64; c++) {
#pragma unroll
    for (int u = 0; u < 3; u++)
#pragma unroll
      for (int v = 0; v < 3; v++) {
        const float* wp = wt + ((c * 3 + u) * 3 + v) * 64 + oc0;
        float4 wa = *(const float4*)wp;
        float4 wb = *(const float4*)(wp + 4);
        const f32x2 w0 = {wa.x, wa.y}, w1 = {wa.z, wa.w};
        const f32x2 w2 = {wb.x, wb.y}, w3 = {wb.z, wb.w};
        int off = c * 81 + u * 9 + v;
#pragma unroll
        for (int k = 0; k < 2; k++) {
          float x = sIn[off + base[k]];
          f32x2 xv = {x, x};
          acc[k][0] = pkfma(w0, xv, acc[k][0]);
          acc[k][1] = pkfma(w1, xv, acc[k][1]);
          acc[k][2] = pkfma(w2, xv, acc[k][2]);
          acc[k][3] = pkfma(w3, xv, acc[k][3]);
        }
      }
  }
  float* op = out + (size_t)b * 3136;
#pragma unroll
  for (int k = 0; k < 2; k++) {
    int p = pg + 32 * k;
    if (p < 49) {
#pragma unroll
      for (int o = 0; o < 8; o++)
        op[(oc0+o)*49 + p] = fmaxf(acc[k][o >> 1][o & 1] + bias[oc0+o], 0.f);
    }
  }
}

// ---- GEMM 64x64 tile: C[M,N] = A[M,K] @ W[N,K]^T + bias, optional relu ----
template<bool RELU>
__global__ __launch_bounds__(256) void gemm_k(
    const float* __restrict__ A, const float* __restrict__ Wm,
    const float* __restrict__ bias, float* __restrict__ C,
    int N, int K) {
  __shared__ __align__(16) float As[16][68];
  __shared__ __align__(16) float Ws[16][68];
  const int t = threadIdx.x;
  const int m0 = blockIdx.y * 64, n0 = blockIdx.x * 64;
  const int r  = t >> 2;
  const int kq = (t & 3) * 4;
  const int r0 = (t >> 4) * 4, c0 = (t & 15) * 4;
  f32x2 acc[4][2];
#pragma unroll
  for (int i = 0; i < 4; i++) { acc[i][0] = f32x2{0.f, 0.f}; acc[i][1] = f32x2{0.f, 0.f}; }
  for (int k0 = 0; k0 < K; k0 += 16) {
    float4 a = *(const float4*)(A + (size_t)(m0 + r) * K + k0 + kq);
    int wrow = n0 + r;
    float4 wv = make_float4(0.f, 0.f, 0.f, 0.f);
    if (wrow < N) wv = *(const float4*)(Wm + (size_t)wrow * K + k0 + kq);
    __syncthreads();
    As[kq+0][r] = a.x; As[kq+1][r] = a.y; As[kq+2][r] = a.z; As[kq+3][r] = a.w;
    Ws[kq+0][r] = wv.x; Ws[kq+1][r] = wv.y; Ws[kq+2][r] = wv.z; Ws[kq+3][r] = wv.w;
    __syncthreads();
#pragma unroll
    for (int kk = 0; kk < 16; kk++) {
      float4 av = *(const float4*)&As[kk][r0];
      float4 bv = *(const float4*)&Ws[kk][c0];
      const f32x2 b0 = {bv.x, bv.y}, b1 = {bv.z, bv.w};
      float ar[4] = {av.x, av.y, av.z, av.w};
#pragma unroll
      for (int i = 0; i < 4; i++) {
        f32x2 ai = {ar[i], ar[i]};
        acc[i][0] = pkfma(b0, ai, acc[i][0]);
        acc[i][1] = pkfma(b1, ai, acc[i][1]);
      }
    }
  }
#pragma unroll
  for (int i = 0; i < 4; i++) {
    int row = m0 + r0 + i;
#pragma unroll
    for (int j = 0; j < 4; j++) {
      int col = n0 + c0 + j;
      if (col < N) {
        float v = acc[i][j >> 1][j & 1] + bias[col];
        C[(size_t)row * N + col] = RELU ? fmaxf(v, 0.f) : v;
      }
    }
  }
}

// ---- GEMM 128x128 tile, 8x8/thread (for large-N m0 matmul). No relu. ----
__global__ __launch_bounds__(256) void gemm128_k(
    const float* __restrict__ A, const float* __restrict__ Wm,
    const float* __restrict__ bias, float* __restrict__ C,
    int N, int K) {
  __shared__ __align__(16) float As[16][132];
  __shared__ __align__(16) float Ws[16][132];
  const int t = threadIdx.x;
  const int m0 = blockIdx.y * 128, n0 = blockIdx.x * 128;
  const int lr = t >> 1;            // 0..127 staging row
  const int kq = (t & 1) * 8;       // 0 or 8
  const int r0 = (t >> 4) * 8, c0 = (t & 15) * 8;
  f32x2 acc[8][4];
#pragma unroll
  for (int i = 0; i < 8; i++)
#pragma unroll
    for (int j = 0; j < 4; j++) acc[i][j] = f32x2{0.f, 0.f};
  for (int k0 = 0; k0 < K; k0 += 16) {
    const float* ap = A + (size_t)(m0 + lr) * K + k0 + kq;
    float4 a0 = *(const float4*)ap;
    float4 a1 = *(const float4*)(ap + 4);
    int wrow = n0 + lr;
    float4 w0 = make_float4(0.f,0.f,0.f,0.f), w1 = make_float4(0.f,0.f,0.f,0.f);
    if (wrow < N) {
      const float* wp = Wm + (size_t)wrow * K + k0 + kq;
      w0 = *(const float4*)wp;
      w1 = *(const float4*)(wp + 4);
    }
    __syncthreads();
    As[kq+0][lr] = a0.x; As[kq+1][lr] = a0.y; As[kq+2][lr] = a0.z; As[kq+3][lr] = a0.w;
    As[kq+4][lr] = a1.x; As[kq+5][lr] = a1.y; As[kq+6][lr] = a1.z; As[kq+7][lr] = a1.w;
    Ws[kq+0][lr] = w0.x; Ws[kq+1][lr] = w0.y; Ws[kq+2][lr] = w0.z; Ws[kq+3][lr] = w0.w;
    Ws[kq+4][lr] = w1.x; Ws[kq+5][lr] = w1.y; Ws[kq+6][lr] = w1.z; Ws[kq+7][lr] = w1.w;
    __syncthreads();
#pragma unroll
    for (int kk = 0; kk < 16; kk++) {
      float4 av0 = *(const float4*)&As[kk][r0];
      float4 av1 = *(const float4*)&As[kk][r0 + 4];
      float4 bv0 = *(const float4*)&Ws[kk][c0];
      float4 bv1 = *(const float4*)&Ws[kk][c0 + 4];
      float ar[8] = {av0.x, av0.y, av0.z, av0.w, av1.x, av1.y, av1.z, av1.w};
      f32x2 br[4] = {{bv0.x, bv0.y}, {bv0.z, bv0.w}, {bv1.x, bv1.y}, {bv1.z, bv1.w}};
#pragma unroll
      for (int i = 0; i < 8; i++) {
        f32x2 ai = {ar[i], ar[i]};
#pragma unroll
        for (int j = 0; j < 4; j++) acc[i][j] = pkfma(br[j], ai, acc[i][j]);
      }
    }
  }
#pragma unroll
  for (int i = 0; i < 8; i++) {
    int row = m0 + r0 + i;
#pragma unroll
    for (int j = 0; j < 8; j++) {
      int col = n0 + c0 + j;
      if (col < N)
        C[(size_t)row * N + col] = acc[i][j >> 1][j & 1] + bias[col];
    }
  }
}

// ---- upconv1: upsample 21->42 + residual 3x3 conv + relu.
//      LDS tile is [pos][ch] (stride 28, 112B rows): fill writes 6xb128,
//      conv reads 6xb128 per tap; weights tap-major [tap][ic][oc] -> SGPR.
__global__ __launch_bounds__(256, 4) void upconv1_k(
    const float* __restrict__ X, const float* __restrict__ wt,
    const float* __restrict__ bias, float* __restrict__ out) {
  constexpr int S_IN = 21, S_OUT = 42, TR = 6, UH = 8, UW = 44, NTILE = 7;
  constexpr int CST = 28;
  __shared__ __align__(16) float sU[UH * UW * CST];   // 9856 floats = 39.4 KB
  const int b = blockIdx.x / NTILE;
  const int y0 = (blockIdx.x % NTILE) * TR;
  const int t = threadIdx.x;
  const float* xb = X + (size_t)b * 24 * S_IN * S_IN;
  const float sc = (float)(S_IN - 1) / (float)(S_OUT - 1);
  for (int rr = t; rr < UH * UW; rr += 256) {
    const int ry = rr / UW, cx = rr % UW;
    const int y = y0 + ry - 1, x = cx - 1;
    float vals[24];
    if (y >= 0 && y < S_OUT && x >= 0 && x < S_OUT) {
      float py = y * sc, px = x * sc;
      int ly = (int)py; if (ly > S_IN - 2) ly = S_IN - 2;
      int lx = (int)px; if (lx > S_IN - 2) lx = S_IN - 2;
      float wy = py - (float)ly, wx = px - (float)lx;
      const f32x2 wxv = {wx, wx};
      const float* xc = xb + ly * S_IN + lx;
      for (int c = 0; c < 24; c++) {
        f32x2 a  = {xc[0], xc[S_IN]};        // {v00, v10}
        f32x2 bb = {xc[1], xc[S_IN + 1]};    // {v01, v11}
        f32x2 h = pkfma(wxv, bb - a, a);     // {h_top, h_bot}
        vals[c] = h[0] + wy * (h[1] - h[0]);
        xc += S_IN * S_IN;
      }
    } else {
#pragma unroll
      for (int c = 0; c < 24; c++) vals[c] = 0.f;
    }
    float4* wd = (float4*)&sU[rr * CST];
#pragma unroll
    for (int w = 0; w < 6; w++)
      wd[w] = make_float4(vals[4*w], vals[4*w+1], vals[4*w+2], vals[4*w+3]);
  }
  __syncthreads();
  if (t < 252) {
    const int ry = t / 42, lx = t % 42;
    f32x2 acc[12];
#pragma unroll
    for (int j = 0; j < 12; j++) acc[j] = f32x2{0.f, 0.f};
    for (int ky = 0; ky < 3; ky++) {
      for (int kx = 0; kx < 3; kx++) {
        const float4* vp = (const float4*)&sU[((ry + ky) * UW + lx + kx) * CST];
        float4 q[6];
#pragma unroll
        for (int w = 0; w < 6; w++) q[w] = vp[w];
        const float* vin = (const float*)q;
        const f32x2* w2 = (const f32x2*)(wt + (ky * 3 + kx) * 576);
#pragma unroll
        for (int ic = 0; ic < 24; ic++) {
          f32x2 xv = {vin[ic], vin[ic]};
#pragma unroll
          for (int j = 0; j < 12; j++)
            acc[j] = pkfma(w2[ic * 12 + j], xv, acc[j]);
        }
      }
    }
    // center (residual) + bias + relu -> global
    const float4* cp = (const float4*)&sU[((ry + 1) * UW + lx + 1) * CST];
    float4 cq[6];
#pragma unroll
    for (int w = 0; w < 6; w++) cq[w] = cp[w];
    const float* cv = (const float*)cq;
    const int yy = y0 + ry;
#pragma unroll
    for (int j = 0; j < 12; j++) {
      float s0 = cv[2*j]     + acc[j][0] + bias[2*j];
      float s1 = cv[2*j + 1] + acc[j][1] + bias[2*j + 1];
      out[(((size_t)b * 24 + 2*j    ) * S_OUT + yy) * S_OUT + lx] = fmaxf(s0, 0.f);
      out[(((size_t)b * 24 + 2*j + 1) * S_OUT + yy) * S_OUT + lx] = fmaxf(s1, 0.f);
    }
  }
}

// ---- fused: upsample 42->84 + residual conv + relu + 1x1 conv + sigmoid
//      + flow + bilinear warp.  [pos][ch] LDS layout as upconv1. ----
__global__ __launch_bounds__(256, 4) void upconv2_final_k(
    const float* __restrict__ R1, const float* __restrict__ inp,
    const float* __restrict__ wt, const float* __restrict__ bias,
    const float* __restrict__ c3w, const float* __restrict__ c3b,
    const float* __restrict__ ot, const float* __restrict__ ct,
    float* __restrict__ out) {
  constexpr int S_IN = 42, S_OUT = 84, TR = 6, UH = 8, TW = 42, UW = 44;
  constexpr int CST = 28;
  __shared__ __align__(16) float sU[UH * UW * CST];   // 9856 floats = 39.4 KB
  const int blk = blockIdx.x;
  const int b = blk / 28;
  const int rr0 = blk % 28;
  const int y0 = (rr0 >> 1) * TR;
  const int x0 = (rr0 & 1) * TW;
  const int t = threadIdx.x;
  const float* xb = R1 + (size_t)b * 24 * S_IN * S_IN;
  const float sc = (float)(S_IN - 1) / (float)(S_OUT - 1);
  for (int rr = t; rr < UH * UW; rr += 256) {
    const int ry = rr / UW, cx = rr % UW;
    const int y = y0 + ry - 1, x = x0 + cx - 1;
    float vals[24];
    if (y >= 0 && y < S_OUT && x >= 0 && x < S_OUT) {
      float py = y * sc, px = x * sc;
      int ly = (int)py; if (ly > S_IN - 2) ly = S_IN - 2;
      int lx = (int)px; if (lx > S_IN - 2) lx = S_IN - 2;
      float wy = py - (float)ly, wx = px - (float)lx;
      const f32x2 wxv = {wx, wx};
      const float* xc = xb + ly * S_IN + lx;
      for (int c = 0; c < 24; c++) {
        f32x2 a  = {xc[0], xc[S_IN]};
        f32x2 bb = {xc[1], xc[S_IN + 1]};
        f32x2 h = pkfma(wxv, bb - a, a);
        vals[c] = h[0] + wy * (h[1] - h[0]);
        xc += S_IN * S_IN;
      }
    } else {
#pragma unroll
      for (int c = 0; c < 24; c++) vals[c] = 0.f;
    }
    float4* wd = (float4*)&sU[rr * CST];
#pragma unroll
    for (int w = 0; w < 6; w++)
      wd[w] = make_float4(vals[4*w], vals[4*w+1], vals[4*w+2], vals[4*w+3]);
  }
  __syncthreads();
  if (t < 252) {
    const int ry = t / 42, lx = t % 42;
    f32x2 acc[12];
#pragma unroll
    for (int j = 0; j < 12; j++) acc[j] = f32x2{0.f, 0.f};
    for (int ky = 0; ky < 3; ky++) {
      for (int kx = 0; kx < 3; kx++) {
        const float4* vp = (const float4*)&sU[((ry + ky) * UW + lx + kx) * CST];
        float4 q[6];
#pragma unroll
        for (int w = 0; w < 6; w++) q[w] = vp[w];
        const float* vin = (const float*)q;
        const f32x2* w2 = (const f32x2*)(wt + (ky * 3 + kx) * 576);
#pragma unroll
        for (int ic = 0; ic < 24; ic++) {
          f32x2 xv = {vin[ic], vin[ic]};
#pragma unroll
          for (int j = 0; j < 12; j++)
            acc[j] = pkfma(w2[ic * 12 + j], xv, acc[j]);
        }
      }
    }
    // residual + relu, kept in register pairs
    const float4* cp = (const float4*)&sU[((ry + 1) * UW + lx + 1) * CST];
    float4 cq[6];
#pragma unroll
    for (int w = 0; w < 6; w++) cq[w] = cp[w];
    const float* cv = (const float*)cq;
    f32x2 r[12];
#pragma unroll
    for (int j = 0; j < 12; j++) {
      r[j][0] = fmaxf(cv[2*j]     + acc[j][0] + bias[2*j],     0.f);
      r[j][1] = fmaxf(cv[2*j + 1] + acc[j][1] + bias[2*j + 1], 0.f);
    }
    // 1x1 conv + sigmoid + flow accumulation (head params uniform -> SGPR)
    f32x2 f2 = *(const f32x2*)&ct[b * 2];            // {fy, fx}
    const f32x2* ot2 = (const f32x2*)(ot + b * 2 * KOBJ);
    for (int k = 0; k < KOBJ; k++) {
      f32x2 zv = {c3b[k], 0.f};
      const f32x2* cw2 = (const f32x2*)(c3w + k * 24);
#pragma unroll
      for (int j = 0; j < 12; j++) zv = pkfma(r[j], cw2[j], zv);
      float z = zv[0] + zv[1];
      float m = 1.f / (1.f + __expf(-z));
      f32x2 mv = {m, m};
      f2 = pkfma(mv, ot2[k], f2);
    }
    const int gy = y0 + ry, gx = x0 + lx;
    const float imgf = 0.01f * 84.0f;
    float ys = imgf * f2[0] + (float)gy;
    float xs = imgf * f2[1] + (float)gx;
    int ix0 = (int)floorf(xs); ix0 = ix0 < 0 ? 0 : (ix0 > 83 ? 83 : ix0);
    int iy0 = (int)floorf(ys); iy0 = iy0 < 0 ? 0 : (iy0 > 83 ? 83 : iy0);
    int ix1 = ix0 + 1 > 83 ? 83 : ix0 + 1;
    int iy1 = iy0 + 1 > 83 ? 83 : iy0 + 1;
    float xc = fminf(fmaxf(xs, 0.f), 83.f);
    float yc = fminf(fmaxf(ys, 0.f), 83.f);
    float wx1 = (float)ix1 - xc, wx0 = xc - (float)ix0;
    float wy1 = (float)iy1 - yc, wy0 = yc - (float)iy0;
    const float* src = inp + ((size_t)b * 2 + 1) * NPIX;
    float Ia = src[iy0 * 84 + ix0], Ib = src[iy1 * 84 + ix0];
    float Ic = src[iy0 * 84 + ix1], Id = src[iy1 * 84 + ix1];
    out[(size_t)b * NPIX + gy * 84 + gx] =
        wx1 * wy1 * Ia + wx1 * wy0 * Ib + wx0 * wy1 * Ic + wx0 * wy0 * Id;
  }
}

}  // namespace

extern "C" void kernel_launch(void* const* d_in, const int* in_sizes, int n_in,
                              void* d_out, int out_size, void* d_ws, size_t ws_size,
                              hipStream_t stream) {
  const float* inp = (const float*)d_in[0];
  const float* cw1 = (const float*)d_in[1];
  const float* cb1 = (const float*)d_in[2];
  const float* cw2 = (const float*)d_in[3];
  const float* cb2 = (const float*)d_in[4];
  const float* cw3 = (const float*)d_in[5];
  const float* cb3 = (const float*)d_in[6];
  const float* fcw = (const float*)d_in[7];
  const float* fcb = (const float*)d_in[8];
  const float* otw = (const float*)d_in[9];
  const float* otb = (const float*)d_in[10];
  const float* ctw = (const float*)d_in[11];
  const float* ctb = (const float*)d_in[12];
  const float* m1w = (const float*)d_in[13];
  const float* m1b = (const float*)d_in[14];
  const float* c1w = (const float*)d_in[15];
  const float* c1b = (const float*)d_in[16];
  const float* c2w = (const float*)d_in[17];
  const float* c2b = (const float*)d_in[18];
  const float* c3w = (const float*)d_in[19];
  const float* c3b = (const float*)d_in[20];
  float* W = (float*)d_ws;
  float* out = (float*)d_out;

  transpose_w<<<(64 * 512 + 255) / 256, 256, 0, stream>>>(cw2, W + OFF_WT2, 64, 512);
  transpose_w<<<(64 * 576 + 255) / 256, 256, 0, stream>>>(cw3, W + OFF_WT3, 64, 576);
  conv1_k<<<512, 256, 0, stream>>>(inp, cw1, cb1, W + OFF_H1);
  conv2_k<<<512, 256, 0, stream>>>(W + OFF_H1, W + OFF_WT2, cb2, W + OFF_H2);
  conv3_k<<<512, 256, 0, stream>>>(W + OFF_H2, W + OFF_WT3, cb3, W + OFF_FEAT);
  // decoder conv weight transposes to tap-major [tap][ic][oc]
  transpose_dec<<<(5184 + 255) / 256, 256, 0, stream>>>(c1w, W + OFF_WT2);
  transpose_dec<<<(5184 + 255) / 256, 256, 0, stream>>>(c2w, W + OFF_WT3);
  // x = relu(feat @ fcw^T + fcb)
  gemm_k<true><<<dim3(8, 8), 256, 0, stream>>>(W + OFF_FEAT, fcw, fcb, W + OFF_X, 512, 3136);
  // heads
  gemm_k<false><<<dim3(1, 8), 256, 0, stream>>>(W + OFF_X, otw, otb, W + OFF_OT, 40, 512);
  gemm_k<false><<<dim3(1, 8), 256, 0, stream>>>(W + OFF_X, ctw, ctb, W + OFF_CT, 2, 512);
  // m0 = x @ m1w^T + m1b   [512, 10584]  (128-tile GEMM, 83x4 blocks)
  gemm128_k<<<dim3(83, 4), 256, 0, stream>>>(W + OFF_X, m1w, m1b, W + OFF_M0, 10584, 512);
  // decoder
  upconv1_k<<<512 * 7, 256, 0, stream>>>(W + OFF_M0, W + OFF_WT2, c1b, W + OFF_R1);
  upconv2_final_k<<<512 * 28, 256, 0, stream>>>(W + OFF_R1, inp, W + OFF_WT3, c2b,
                                                c3w, c3b, W + OFF_OT, W + OFF_CT, out);
}

// Round 6
// 1102.729 us; speedup vs baseline: 1.2099x; 1.2099x over previous
//
#include <hip/hip_runtime.h>
#include <math.h>

namespace {

typedef float f32x2 __attribute__((ext_vector_type(2)));

#if defined(__has_builtin)
#if __has_builtin(__builtin_elementwise_fma)
#define HAVE_EW_FMA 1
#endif
#endif

__device__ __forceinline__ f32x2 pkfma(f32x2 a, f32x2 b, f32x2 c) {
#ifdef HAVE_EW_FMA
  return __builtin_elementwise_fma(a, b, c);
#else
  return a * b + c;   // -ffp-contract=fast fuses per element
#endif
}

constexpr int IMS  = 84;
constexpr int NPIX = IMS * IMS;      // 7056
constexpr int KOBJ = 20;

// ---- workspace layout (float offsets), peak = 27448320 floats = 110 MB ----
constexpr size_t OFF_X    = 0;            // 512*512            -> 262144
constexpr size_t OFF_OT   = 262144;       // 512*40             -> 282624
constexpr size_t OFF_CT   = 282624;       // 512*2 (pad)        -> 283648
constexpr size_t OFF_WT2  = 283648;       // 512*64             -> 316416
constexpr size_t OFF_WT3  = 316416;       // 576*64             -> 353280
constexpr size_t OFF_M0   = 353280;       // 512*10584          -> 5772288
constexpr size_t OFF_R1   = 5772288;      // 512*24*42*42       -> 27448320
// H1/H2/FEAT alias into the R1 region (dead before upconv1 writes R1)
constexpr size_t OFF_H1   = OFF_R1;       // 512*32*400         -> 12325888
constexpr size_t OFF_H2   = 12325888;     // 512*64*81          -> 14980096
constexpr size_t OFF_FEAT = 14980096;     // 512*3136           -> 16585728
// fcw split-K partials live in OFF_M0 (dead until the m0 GEMM runs)

// ---- generic weight transpose: w[oc][ckk] -> wt[ckk][oc] ----
__global__ void transpose_w(const float* __restrict__ w, float* __restrict__ wt,
                            int OC, int CKK) {
  int idx = blockIdx.x * 256 + threadIdx.x;
  if (idx < OC * CKK) {
    int oc = idx / CKK, ckk = idx % CKK;
    wt[ckk * OC + oc] = w[idx];
  }
}

// ---- conv1: [B,2,84,84] -> [B,32,20,20], k=8 s=4, relu. LDS 44.6 KB ----
__global__ __launch_bounds__(256) void conv1_k(
    const float* __restrict__ inp, const float* __restrict__ w,
    const float* __restrict__ bias, float* __restrict__ out) {
  __shared__ __align__(16) float sIn[NPIX];      // one channel at a time
  __shared__ __align__(16) float sW[128 * 32];   // [c][u][v][oc]
  const int b = blockIdx.x, t = threadIdx.x;
  for (int i = t; i < 4096; i += 256) {
    int oc = i >> 7, ckk = i & 127;
    sW[ckk * 32 + oc] = w[i];
  }
  const float* ip = inp + (size_t)b * 2 * NPIX;
  const int oc0 = (t & 7) * 4;
  const int pg  = t >> 3;
  int ibase[13];
#pragma unroll
  for (int k = 0; k < 13; k++) {
    int p = pg + 32 * k; if (p > 399) p = 399;
    ibase[k] = (p / 20) * 4 * 84 + (p % 20) * 4;
  }
  f32x2 acc[13][2];
#pragma unroll
  for (int k = 0; k < 13; k++) { acc[k][0] = f32x2{0.f, 0.f}; acc[k][1] = f32x2{0.f, 0.f}; }
  for (int c = 0; c < 2; c++) {
    __syncthreads();
    for (int i = t; i < NPIX; i += 256) sIn[i] = ip[c * NPIX + i];
    __syncthreads();
    for (int u = 0; u < 8; u++) {
#pragma unroll
      for (int v = 0; v < 8; v++) {
        const float4 wv = *(const float4*)&sW[((c * 8 + u) * 8 + v) * 32 + oc0];
        const f32x2 w0 = {wv.x, wv.y}, w1 = {wv.z, wv.w};
        const int off = u * 84 + v;
#pragma unroll
        for (int k = 0; k < 13; k++) {
          float x = sIn[off + ibase[k]];
          f32x2 xv = {x, x};
          acc[k][0] = pkfma(w0, xv, acc[k][0]);
          acc[k][1] = pkfma(w1, xv, acc[k][1]);
        }
      }
    }
  }
  float b0 = bias[oc0], b1 = bias[oc0+1], b2 = bias[oc0+2], b3 = bias[oc0+3];
  float* op = out + (size_t)b * 32 * 400;
#pragma unroll
  for (int k = 0; k < 13; k++) {
    int p = pg + 32 * k;
    if (p < 400) {
      op[(oc0+0)*400 + p] = fmaxf(acc[k][0][0] + b0, 0.f);
      op[(oc0+1)*400 + p] = fmaxf(acc[k][0][1] + b1, 0.f);
      op[(oc0+2)*400 + p] = fmaxf(acc[k][1][0] + b2, 0.f);
      op[(oc0+3)*400 + p] = fmaxf(acc[k][1][1] + b3, 0.f);
    }
  }
}

// ---- conv2: [B,32,20,20] -> [B,64,9,9], k=4 s=2, relu. LDS 51.2 KB ----
__global__ __launch_bounds__(256) void conv2_k(
    const float* __restrict__ in, const float* __restrict__ wt,
    const float* __restrict__ bias, float* __restrict__ out) {
  __shared__ float sIn[32 * 400];
  const int b = blockIdx.x, t = threadIdx.x;
  const float* ip = in + (size_t)b * 12800;
  for (int i = t; i < 12800; i += 256) sIn[i] = ip[i];
  __syncthreads();
  const int oc0 = (t & 7) * 8;
  const int pg  = t >> 3;
  int base[3];
#pragma unroll
  for (int k = 0; k < 3; k++) {
    int p = pg + 32 * k; if (p > 80) p = 80;
    base[k] = (p / 9) * 40 + (p % 9) * 2;
  }
  f32x2 acc[3][4];
#pragma unroll
  for (int k = 0; k < 3; k++)
#pragma unroll
    for (int o = 0; o < 4; o++) acc[k][o] = f32x2{0.f, 0.f};
  for (int c = 0; c < 32; c++) {
#pragma unroll
    for (int u = 0; u < 4; u++)
#pragma unroll
      for (int v = 0; v < 4; v++) {
        const float* wp = wt + ((c * 4 + u) * 4 + v) * 64 + oc0;
        float4 wa = *(const float4*)wp;
        float4 wb = *(const float4*)(wp + 4);
        const f32x2 w0 = {wa.x, wa.y}, w1 = {wa.z, wa.w};
        const f32x2 w2 = {wb.x, wb.y}, w3 = {wb.z, wb.w};
        int off = c * 400 + u * 20 + v;
#pragma unroll
        for (int k = 0; k < 3; k++) {
          float x = sIn[off + base[k]];
          f32x2 xv = {x, x};
          acc[k][0] = pkfma(w0, xv, acc[k][0]);
          acc[k][1] = pkfma(w1, xv, acc[k][1]);
          acc[k][2] = pkfma(w2, xv, acc[k][2]);
          acc[k][3] = pkfma(w3, xv, acc[k][3]);
        }
      }
  }
  float* op = out + (size_t)b * 5184;
#pragma unroll
  for (int k = 0; k < 3; k++) {
    int p = pg + 32 * k;
    if (p < 81) {
#pragma unroll
      for (int o = 0; o < 8; o++)
        op[(oc0+o)*81 + p] = fmaxf(acc[k][o >> 1][o & 1] + bias[oc0+o], 0.f);
    }
  }
}

// ---- conv3: [B,64,9,9] -> feat [B,3136] (= [64][7][7] flat), k=3 s=1, relu ----
__global__ __launch_bounds__(256) void conv3_k(
    const float* __restrict__ in, const float* __restrict__ wt,
    const float* __restrict__ bias, float* __restrict__ out) {
  __shared__ float sIn[64 * 81];
  const int b = blockIdx.x, t = threadIdx.x;
  const float* ip = in + (size_t)b * 5184;
  for (int i = t; i < 5184; i += 256) sIn[i] = ip[i];
  __syncthreads();
  const int oc0 = (t & 7) * 8;
  const int pg  = t >> 3;
  int base[2];
#pragma unroll
  for (int k = 0; k < 2; k++) {
    int p = pg + 32 * k; if (p > 48) p = 48;
    base[k] = (p / 7) * 9 + (p % 7);
  }
  f32x2 acc[2][4];
#pragma unroll
  for (int k = 0; k < 2; k++)
#pragma unroll
    for (int o = 0; o < 4; o++) acc[k][o] = f32x2{0.f, 0.f};
  for (int c = 0; c < 64; c++) {
#pragma unroll
    for (int u = 0; u < 3; u++)
#pragma unroll
      for (int v = 0; v < 3; v++) {
        const float* wp = wt + ((c * 3 + u) * 3 + v) * 64 + oc0;
        float4 wa = *(const float4*)wp;
        float4 wb = *(const float4*)(wp + 4);
        const f32x2 w0 = {wa.x, wa.y}, w1 = {wa.z, wa.w};
        const f32x2 w2 = {wb.x, wb.y}, w3 = {wb.z, wb.w};
        int off = c * 81 + u * 9 + v;
#pragma unroll
        for (int k = 0; k < 2; k++) {
          float x = sIn[off + base[k]];
          f32x2 xv = {x, x};
          acc[k][0] = pkfma(w0, xv, acc[k][0]);
          acc[k][1] = pkfma(w1, xv, acc[k][1]);
          acc[k][2] = pkfma(w2, xv, acc[k][2]);
          acc[k][3] = pkfma(w3, xv, acc[k][3]);
        }
      }
  }
  float* op = out + (size_t)b * 3136;
#pragma unroll
  for (int k = 0; k < 2; k++) {
    int p = pg + 32 * k;
    if (p < 49) {
#pragma unroll
      for (int o = 0; o < 8; o++)
        op[(oc0+o)*49 + p] = fmaxf(acc[k][o >> 1][o & 1] + bias[oc0+o], 0.f);
    }
  }
}

// ---- GEMM 64x64 tile: C[M,N] = A[M,K] @ W[N,K]^T + bias, optional relu ----
template<bool RELU>
__global__ __launch_bounds__(256) void gemm_k(
    const float* __restrict__ A, const float* __restrict__ Wm,
    const float* __restrict__ bias, float* __restrict__ C,
    int N, int K) {
  __shared__ __align__(16) float As[16][68];
  __shared__ __align__(16) float Ws[16][68];
  const int t = threadIdx.x;
  const int m0 = blockIdx.y * 64, n0 = blockIdx.x * 64;
  const int r  = t >> 2;
  const int kq = (t & 3) * 4;
  const int r0 = (t >> 4) * 4, c0 = (t & 15) * 4;
  f32x2 acc[4][2];
#pragma unroll
  for (int i = 0; i < 4; i++) { acc[i][0] = f32x2{0.f, 0.f}; acc[i][1] = f32x2{0.f, 0.f}; }
  for (int k0 = 0; k0 < K; k0 += 16) {
    float4 a = *(const float4*)(A + (size_t)(m0 + r) * K + k0 + kq);
    int wrow = n0 + r;
    float4 wv = make_float4(0.f, 0.f, 0.f, 0.f);
    if (wrow < N) wv = *(const float4*)(Wm + (size_t)wrow * K + k0 + kq);
    __syncthreads();
    As[kq+0][r] = a.x; As[kq+1][r] = a.y; As[kq+2][r] = a.z; As[kq+3][r] = a.w;
    Ws[kq+0][r] = wv.x; Ws[kq+1][r] = wv.y; Ws[kq+2][r] = wv.z; Ws[kq+3][r] = wv.w;
    __syncthreads();
#pragma unroll
    for (int kk = 0; kk < 16; kk++) {
      float4 av = *(const float4*)&As[kk][r0];
      float4 bv = *(const float4*)&Ws[kk][c0];
      const f32x2 b0 = {bv.x, bv.y}, b1 = {bv.z, bv.w};
      float ar[4] = {av.x, av.y, av.z, av.w};
#pragma unroll
      for (int i = 0; i < 4; i++) {
        f32x2 ai = {ar[i], ar[i]};
        acc[i][0] = pkfma(b0, ai, acc[i][0]);
        acc[i][1] = pkfma(b1, ai, acc[i][1]);
      }
    }
  }
#pragma unroll
  for (int i = 0; i < 4; i++) {
    int row = m0 + r0 + i;
#pragma unroll
    for (int j = 0; j < 4; j++) {
      int col = n0 + c0 + j;
      if (col < N) {
        float v = acc[i][j >> 1][j & 1] + bias[col];
        C[(size_t)row * N + col] = RELU ? fmaxf(v, 0.f) : v;
      }
    }
  }
}

// ---- split-K GEMM (no bias/relu): Cpart[z][M][N] partial over K-slice ----
__global__ __launch_bounds__(256) void gemm_splitk_k(
    const float* __restrict__ A, const float* __restrict__ Wm,
    float* __restrict__ Cpart, int N, int K, int Kslice) {
  __shared__ __align__(16) float As[16][68];
  __shared__ __align__(16) float Ws[16][68];
  const int t = threadIdx.x;
  const int m0 = blockIdx.y * 64, n0 = blockIdx.x * 64;
  const int kbeg = blockIdx.z * Kslice;
  const int kend = kbeg + Kslice;
  const int r  = t >> 2;
  const int kq = (t & 3) * 4;
  const int r0 = (t >> 4) * 4, c0 = (t & 15) * 4;
  f32x2 acc[4][2];
#pragma unroll
  for (int i = 0; i < 4; i++) { acc[i][0] = f32x2{0.f, 0.f}; acc[i][1] = f32x2{0.f, 0.f}; }
  for (int k0 = kbeg; k0 < kend; k0 += 16) {
    float4 a = *(const float4*)(A + (size_t)(m0 + r) * K + k0 + kq);
    float4 wv = *(const float4*)(Wm + (size_t)(n0 + r) * K + k0 + kq);
    __syncthreads();
    As[kq+0][r] = a.x; As[kq+1][r] = a.y; As[kq+2][r] = a.z; As[kq+3][r] = a.w;
    Ws[kq+0][r] = wv.x; Ws[kq+1][r] = wv.y; Ws[kq+2][r] = wv.z; Ws[kq+3][r] = wv.w;
    __syncthreads();
#pragma unroll
    for (int kk = 0; kk < 16; kk++) {
      float4 av = *(const float4*)&As[kk][r0];
      float4 bv = *(const float4*)&Ws[kk][c0];
      const f32x2 b0 = {bv.x, bv.y}, b1 = {bv.z, bv.w};
      float ar[4] = {av.x, av.y, av.z, av.w};
#pragma unroll
      for (int i = 0; i < 4; i++) {
        f32x2 ai = {ar[i], ar[i]};
        acc[i][0] = pkfma(b0, ai, acc[i][0]);
        acc[i][1] = pkfma(b1, ai, acc[i][1]);
      }
    }
  }
  float* cp = Cpart + (size_t)blockIdx.z * 512 * 512;
#pragma unroll
  for (int i = 0; i < 4; i++) {
    int row = m0 + r0 + i;
#pragma unroll
    for (int j = 0; j < 4; j++)
      cp[(size_t)row * N + n0 + c0 + j] = acc[i][j >> 1][j & 1];
  }
}

// ---- reduce 4 split-K partials + bias + relu -> X [512][512] ----
__global__ __launch_bounds__(256) void splitk_reduce_k(
    const float* __restrict__ Cpart, const float* __restrict__ bias,
    float* __restrict__ X) {
  int i4 = blockIdx.x * 256 + threadIdx.x;     // float4 index over 512*512/4
  if (i4 < 65536) {
    int col4 = (i4 & 127) * 4;
    float4 p0 = *(const float4*)&Cpart[(size_t)i4 * 4];
    float4 p1 = *(const float4*)&Cpart[262144 + (size_t)i4 * 4];
    float4 p2 = *(const float4*)&Cpart[524288 + (size_t)i4 * 4];
    float4 p3 = *(const float4*)&Cpart[786432 + (size_t)i4 * 4];
    float4 bb = *(const float4*)&bias[col4];
    float4 o;
    o.x = fmaxf(p0.x + p1.x + p2.x + p3.x + bb.x, 0.f);
    o.y = fmaxf(p0.y + p1.y + p2.y + p3.y + bb.y, 0.f);
    o.z = fmaxf(p0.z + p1.z + p2.z + p3.z + bb.z, 0.f);
    o.w = fmaxf(p0.w + p1.w + p2.w + p3.w + bb.w, 0.f);
    *(float4*)&X[(size_t)i4 * 4] = o;
  }
}

// ---- GEMM 128x128 tile, 8x8/thread (for large-N m0 matmul). No relu. ----
__global__ __launch_bounds__(256) void gemm128_k(
    const float* __restrict__ A, const float* __restrict__ Wm,
    const float* __restrict__ bias, float* __restrict__ C,
    int N, int K) {
  __shared__ __align__(16) float As[16][132];
  __shared__ __align__(16) float Ws[16][132];
  const int t = threadIdx.x;
  const int m0 = blockIdx.y * 128, n0 = blockIdx.x * 128;
  const int lr = t >> 1;            // 0..127 staging row
  const int kq = (t & 1) * 8;       // 0 or 8
  const int r0 = (t >> 4) * 8, c0 = (t & 15) * 8;
  f32x2 acc[8][4];
#pragma unroll
  for (int i = 0; i < 8; i++)
#pragma unroll
    for (int j = 0; j < 4; j++) acc[i][j] = f32x2{0.f, 0.f};
  for (int k0 = 0; k0 < K; k0 += 16) {
    const float* ap = A + (size_t)(m0 + lr) * K + k0 + kq;
    float4 a0 = *(const float4*)ap;
    float4 a1 = *(const float4*)(ap + 4);
    int wrow = n0 + lr;
    float4 w0 = make_float4(0.f,0.f,0.f,0.f), w1 = make_float4(0.f,0.f,0.f,0.f);
    if (wrow < N) {
      const float* wp = Wm + (size_t)wrow * K + k0 + kq;
      w0 = *(const float4*)wp;
      w1 = *(const float4*)(wp + 4);
    }
    __syncthreads();
    As[kq+0][lr] = a0.x; As[kq+1][lr] = a0.y; As[kq+2][lr] = a0.z; As[kq+3][lr] = a0.w;
    As[kq+4][lr] = a1.x; As[kq+5][lr] = a1.y; As[kq+6][lr] = a1.z; As[kq+7][lr] = a1.w;
    Ws[kq+0][lr] = w0.x; Ws[kq+1][lr] = w0.y; Ws[kq+2][lr] = w0.z; Ws[kq+3][lr] = w0.w;
    Ws[kq+4][lr] = w1.x; Ws[kq+5][lr] = w1.y; Ws[kq+6][lr] = w1.z; Ws[kq+7][lr] = w1.w;
    __syncthreads();
#pragma unroll
    for (int kk = 0; kk < 16; kk++) {
      float4 av0 = *(const float4*)&As[kk][r0];
      float4 av1 = *(const float4*)&As[kk][r0 + 4];
      float4 bv0 = *(const float4*)&Ws[kk][c0];
      float4 bv1 = *(const float4*)&Ws[kk][c0 + 4];
      float ar[8] = {av0.x, av0.y, av0.z, av0.w, av1.x, av1.y, av1.z, av1.w};
      f32x2 br[4] = {{bv0.x, bv0.y}, {bv0.z, bv0.w}, {bv1.x, bv1.y}, {bv1.z, bv1.w}};
#pragma unroll
      for (int i = 0; i < 8; i++) {
        f32x2 ai = {ar[i], ar[i]};
#pragma unroll
        for (int j = 0; j < 4; j++) acc[i][j] = pkfma(br[j], ai, acc[i][j]);
      }
    }
  }
#pragma unroll
  for (int i = 0; i < 8; i++) {
    int row = m0 + r0 + i;
#pragma unroll
    for (int j = 0; j < 8; j++) {
      int col = n0 + c0 + j;
      if (col < N)
        C[(size_t)row * N + col] = acc[i][j >> 1][j & 1] + bias[col];
    }
  }
}

// ---- upconv1: upsample 21->42 + residual 3x3 conv + relu.
//      [ch][pos] LDS layout (round-3 best).  384 threads: balanced fill
//      (1 position/thread) and 24 waves/CU residency.  LDS 33.8 KB. ----
__global__ __launch_bounds__(384, 6) void upconv1_k(
    const float* __restrict__ X, const float* __restrict__ wt,
    const float* __restrict__ bias, float* __restrict__ out) {
  constexpr int S_IN = 21, S_OUT = 42, TR = 6, UH = 8, UW = 44, NTILE = 7;
  __shared__ __align__(16) float sU[24 * UH * UW];   // 8448 floats = 33 KB
  const int b = blockIdx.x / NTILE;
  const int y0 = (blockIdx.x % NTILE) * TR;
  const int t = threadIdx.x;
  const float* xb = X + (size_t)b * 24 * S_IN * S_IN;
  const float sc = (float)(S_IN - 1) / (float)(S_OUT - 1);
  for (int rr = t; rr < UH * UW; rr += 384) {
    const int ry = rr / UW, cx = rr % UW;
    const int y = y0 + ry - 1, x = cx - 1;
    float* sdst = &sU[rr];
    if (y >= 0 && y < S_OUT && x >= 0 && x < S_OUT) {
      float py = y * sc, px = x * sc;
      int ly = (int)py; if (ly > S_IN - 2) ly = S_IN - 2;
      int lx = (int)px; if (lx > S_IN - 2) lx = S_IN - 2;
      float wy = py - (float)ly, wx = px - (float)lx;
      const f32x2 wxv = {wx, wx};
      const float* xc = xb + ly * S_IN + lx;
      for (int c = 0; c < 24; c++) {
        f32x2 a  = {xc[0], xc[S_IN]};        // {v00, v10}
        f32x2 bb = {xc[1], xc[S_IN + 1]};    // {v01, v11}
        f32x2 h = pkfma(wxv, bb - a, a);     // {h_top, h_bot}
        *sdst = h[0] + wy * (h[1] - h[0]);
        xc += S_IN * S_IN;
        sdst += UH * UW;
      }
    } else {
      for (int c = 0; c < 24; c++) { *sdst = 0.f; sdst += UH * UW; }
    }
  }
  __syncthreads();
  if (t < 252) {
    const int ry = t / 42, lx = t % 42;
    f32x2 acc[12];
#pragma unroll
    for (int j = 0; j < 12; j++) acc[j] = f32x2{0.f, 0.f};
    for (int ic = 0; ic < 24; ic++) {
      const float* urow = &sU[(ic * UH + ry) * UW + lx];
      const float* wp = wt + ic * 216;   // [3][3][24], uniform -> s_load
#pragma unroll
      for (int ky = 0; ky < 3; ky++) {
        float x0v = urow[ky * UW + 0];
        float x1v = urow[ky * UW + 1];
        float x2v = urow[ky * UW + 2];
        f32x2 X0 = {x0v, x0v}, X1 = {x1v, x1v}, X2 = {x2v, x2v};
        const f32x2* wk2 = (const f32x2*)(wp + ky * 72);
#pragma unroll
        for (int j = 0; j < 12; j++)
          acc[j] = pkfma(wk2[j], X0,
                   pkfma(wk2[12 + j], X1,
                   pkfma(wk2[24 + j], X2, acc[j])));
      }
    }
    const int yy = y0 + ry;
#pragma unroll
    for (int j = 0; j < 12; j++) {
      f32x2 u2 = { sU[((2*j)   * UH + ry + 1) * UW + lx + 1],
                   sU[((2*j+1) * UH + ry + 1) * UW + lx + 1] };
      f32x2 b2 = *(const f32x2*)&bias[2*j];
      f32x2 s = u2 + acc[j] + b2;
      out[(((size_t)b * 24 + 2*j    ) * S_OUT + yy) * S_OUT + lx] = fmaxf(s[0], 0.f);
      out[(((size_t)b * 24 + 2*j + 1) * S_OUT + yy) * S_OUT + lx] = fmaxf(s[1], 0.f);
    }
  }
}

// ---- fused: upsample 42->84 + residual conv + relu + 1x1 conv + sigmoid
//      + flow + bilinear warp.  [ch][pos] layout, 384 threads. ----
__global__ __launch_bounds__(384, 6) void upconv2_final_k(
    const float* __restrict__ R1, const float* __restrict__ inp,
    const float* __restrict__ wt, const float* __restrict__ bias,
    const float* __restrict__ c3w, const float* __restrict__ c3b,
    const float* __restrict__ ot, const float* __restrict__ ct,
    float* __restrict__ out) {
  constexpr int S_IN = 42, S_OUT = 84, TR = 6, UH = 8, TW = 42, UW = 44;
  __shared__ __align__(16) float sU[24 * UH * UW];   // 8448 floats = 33 KB
  const int blk = blockIdx.x;
  const int b = blk / 28;
  const int rr0 = blk % 28;
  const int y0 = (rr0 >> 1) * TR;
  const int x0 = (rr0 & 1) * TW;
  const int t = threadIdx.x;
  const float* xb = R1 + (size_t)b * 24 * S_IN * S_IN;
  const float sc = (float)(S_IN - 1) / (float)(S_OUT - 1);
  for (int rr = t; rr < UH * UW; rr += 384) {
    const int ry = rr / UW, cx = rr % UW;
    const int y = y0 + ry - 1, x = x0 + cx - 1;
    float* sdst = &sU[rr];
    if (y >= 0 && y < S_OUT && x >= 0 && x < S_OUT) {
      float py = y * sc, px = x * sc;
      int ly = (int)py; if (ly > S_IN - 2) ly = S_IN - 2;
      int lx = (int)px; if (lx > S_IN - 2) lx = S_IN - 2;
      float wy = py - (float)ly, wx = px - (float)lx;
      const f32x2 wxv = {wx, wx};
      const float* xc = xb + ly * S_IN + lx;
      for (int c = 0; c < 24; c++) {
        f32x2 a  = {xc[0], xc[S_IN]};
        f32x2 bb = {xc[1], xc[S_IN + 1]};
        f32x2 h = pkfma(wxv, bb - a, a);
        *sdst = h[0] + wy * (h[1] - h[0]);
        xc += S_IN * S_IN;
        sdst += UH * UW;
      }
    } else {
      for (int c = 0; c < 24; c++) { *sdst = 0.f; sdst += UH * UW; }
    }
  }
  __syncthreads();
  if (t < 252) {
    const int ry = t / 42, lx = t % 42;
    f32x2 acc[12];
#pragma unroll
    for (int j = 0; j < 12; j++) acc[j] = f32x2{0.f, 0.f};
    for (int ic = 0; ic < 24; ic++) {
      const float* urow = &sU[(ic * UH + ry) * UW + lx];
      const float* wp = wt + ic * 216;   // uniform -> s_load
#pragma unroll
      for (int ky = 0; ky < 3; ky++) {
        float x0v = urow[ky * UW + 0];
        float x1v = urow[ky * UW + 1];
        float x2v = urow[ky * UW + 2];
        f32x2 X0 = {x0v, x0v}, X1 = {x1v, x1v}, X2 = {x2v, x2v};
        const f32x2* wk2 = (const f32x2*)(wp + ky * 72);
#pragma unroll
        for (int j = 0; j < 12; j++)
          acc[j] = pkfma(wk2[j], X0,
                   pkfma(wk2[12 + j], X1,
                   pkfma(wk2[24 + j], X2, acc[j])));
      }
    }
    // residual + relu, kept in register pairs
    f32x2 r[12];
#pragma unroll
    for (int j = 0; j < 12; j++) {
      f32x2 u2 = { sU[((2*j)   * UH + ry + 1) * UW + lx + 1],
                   sU[((2*j+1) * UH + ry + 1) * UW + lx + 1] };
      f32x2 b2 = *(const f32x2*)&bias[2*j];
      f32x2 s = u2 + acc[j] + b2;
      r[j][0] = fmaxf(s[0], 0.f);
      r[j][1] = fmaxf(s[1], 0.f);
    }
    // 1x1 conv + sigmoid + flow accumulation (head params uniform -> SGPR)
    f32x2 f2 = *(const f32x2*)&ct[b * 2];            // {fy, fx}
    const f32x2* ot2 = (const f32x2*)(ot + b * 2 * KOBJ);
    for (int k = 0; k < KOBJ; k++) {
      f32x2 zv = {c3b[k], 0.f};
      const f32x2* cw2 = (const f32x2*)(c3w + k * 24);
#pragma unroll
      for (int j = 0; j < 12; j++) zv = pkfma(r[j], cw2[j], zv);
      float z = zv[0] + zv[1];
      float m = 1.f / (1.f + __expf(-z));
      f32x2 mv = {m, m};
      f2 = pkfma(mv, ot2[k], f2);
    }
    const int gy = y0 + ry, gx = x0 + lx;
    const float imgf = 0.01f * 84.0f;
    float ys = imgf * f2[0] + (float)gy;
    float xs = imgf * f2[1] + (float)gx;
    int ix0 = (int)floorf(xs); ix0 = ix0 < 0 ? 0 : (ix0 > 83 ? 83 : ix0);
    int iy0 = (int)floorf(ys); iy0 = iy0 < 0 ? 0 : (iy0 > 83 ? 83 : iy0);
    int ix1 = ix0 + 1 > 83 ? 83 : ix0 + 1;
    int iy1 = iy0 + 1 > 83 ? 83 : iy0 + 1;
    float xc = fminf(fmaxf(xs, 0.f), 83.f);
    float yc = fminf(fmaxf(ys, 0.f), 83.f);
    float wx1 = (float)ix1 - xc, wx0 = xc - (float)ix0;
    float wy1 = (float)iy1 - yc, wy0 = yc - (float)iy0;
    const float* src = inp + ((size_t)b * 2 + 1) * NPIX;
    float Ia = src[iy0 * 84 + ix0], Ib = src[iy1 * 84 + ix0];
    float Ic = src[iy0 * 84 + ix1], Id = src[iy1 * 84 + ix1];
    out[(size_t)b * NPIX + gy * 84 + gx] =
        wx1 * wy1 * Ia + wx1 * wy0 * Ib + wx0 * wy1 * Ic + wx0 * wy0 * Id;
  }
}

}  // namespace

extern "C" void kernel_launch(void* const* d_in, const int* in_sizes, int n_in,
                              void* d_out, int out_size, void* d_ws, size_t ws_size,
                              hipStream_t stream) {
  const float* inp = (const float*)d_in[0];
  const float* cw1 = (const float*)d_in[1];
  const float* cb1 = (const float*)d_in[2];
  const float* cw2 = (const float*)d_in[3];
  const float* cb2 = (const float*)d_in[4];
  const float* cw3 = (const float*)d_in[5];
  const float* cb3 = (const float*)d_in[6];
  const float* fcw = (const float*)d_in[7];
  const float* fcb = (const float*)d_in[8];
  const float* otw = (const float*)d_in[9];
  const float* otb = (const float*)d_in[10];
  const float* ctw = (const float*)d_in[11];
  const float* ctb = (const float*)d_in[12];
  const float* m1w = (const float*)d_in[13];
  const float* m1b = (const float*)d_in[14];
  const float* c1w = (const float*)d_in[15];
  const float* c1b = (const float*)d_in[16];
  const float* c2w = (const float*)d_in[17];
  const float* c2b = (const float*)d_in[18];
  const float* c3w = (const float*)d_in[19];
  const float* c3b = (const float*)d_in[20];
  float* W = (float*)d_ws;
  float* out = (float*)d_out;

  transpose_w<<<(64 * 512 + 255) / 256, 256, 0, stream>>>(cw2, W + OFF_WT2, 64, 512);
  transpose_w<<<(64 * 576 + 255) / 256, 256, 0, stream>>>(cw3, W + OFF_WT3, 64, 576);
  conv1_k<<<512, 256, 0, stream>>>(inp, cw1, cb1, W + OFF_H1);
  conv2_k<<<512, 256, 0, stream>>>(W + OFF_H1, W + OFF_WT2, cb2, W + OFF_H2);
  conv3_k<<<512, 256, 0, stream>>>(W + OFF_H2, W + OFF_WT3, cb3, W + OFF_FEAT);
  // decoder conv weight transposes: [24][24][3][3] -> [ic*9+tap][oc]
  transpose_w<<<(24 * 216 + 255) / 256, 256, 0, stream>>>(c1w, W + OFF_WT2, 24, 216);
  transpose_w<<<(24 * 216 + 255) / 256, 256, 0, stream>>>(c2w, W + OFF_WT3, 24, 216);
  // x = relu(feat @ fcw^T + fcb)  -- split-K x4 (partials in dead OFF_M0)
  gemm_splitk_k<<<dim3(8, 8, 4), 256, 0, stream>>>(W + OFF_FEAT, fcw, W + OFF_M0,
                                                   512, 3136, 784);
  splitk_reduce_k<<<256, 256, 0, stream>>>(W + OFF_M0, fcb, W + OFF_X);
  // heads
  gemm_k<false><<<dim3(1, 8), 256, 0, stream>>>(W + OFF_X, otw, otb, W + OFF_OT, 40, 512);
  gemm_k<false><<<dim3(1, 8), 256, 0, stream>>>(W + OFF_X, ctw, ctb, W + OFF_CT, 2, 512);
  // m0 = x @ m1w^T + m1b   [512, 10584]  (128-tile GEMM, 83x4 blocks)
  gemm128_k<<<dim3(83, 4), 256, 0, stream>>>(W + OFF_X, m1w, m1b, W + OFF_M0, 10584, 512);
  // decoder
  upconv1_k<<<512 * 7, 384, 0, stream>>>(W + OFF_M0, W + OFF_WT2, c1b, W + OFF_R1);
  upconv2_final_k<<<512 * 28, 384, 0, stream>>>(W + OFF_R1, inp, W + OFF_WT3, c2b,
                                                c3w, c3b, W + OFF_OT, W + OFF_CT, out);
}

// Round 7
// 1076.417 us; speedup vs baseline: 1.2395x; 1.0244x over previous
//
#include <hip/hip_runtime.h>
#include <math.h>

namespace {

typedef float f32x2 __attribute__((ext_vector_type(2)));
typedef float f32x4 __attribute__((ext_vector_type(4)));

#if defined(__has_builtin)
#if __has_builtin(__builtin_elementwise_fma)
#define HAVE_EW_FMA 1
#endif
#endif

__device__ __forceinline__ f32x2 pkfma(f32x2 a, f32x2 b, f32x2 c) {
#ifdef HAVE_EW_FMA
  return __builtin_elementwise_fma(a, b, c);
#else
  return a * b + c;
#endif
}
__device__ __forceinline__ f32x4 fma4(f32x4 a, f32x4 b, f32x4 c) {
#ifdef HAVE_EW_FMA
  return __builtin_elementwise_fma(a, b, c);
#else
  return a * b + c;
#endif
}

constexpr int IMS  = 84;
constexpr int NPIX = IMS * IMS;      // 7056
constexpr int KOBJ = 20;

// ---- workspace layout (float offsets), peak = 27448320 floats = 110 MB ----
constexpr size_t OFF_X    = 0;            // 512*512            -> 262144
constexpr size_t OFF_OT   = 262144;       // 512*40             -> 282624
constexpr size_t OFF_CT   = 282624;       // 512*2 (pad)        -> 283648
constexpr size_t OFF_WT2  = 283648;       // 512*64             -> 316416
constexpr size_t OFF_WT3  = 316416;       // 576*64             -> 353280
constexpr size_t OFF_M0   = 353280;       // 512*10584          -> 5772288
constexpr size_t OFF_R1   = 5772288;      // 512*24*42*42 (R1T) -> 27448320
// H1/H2/FEAT alias into the R1 region (dead before upconv1 writes R1)
constexpr size_t OFF_H1   = OFF_R1;       // 512*32*400         -> 12325888
constexpr size_t OFF_H2   = 12325888;     // 512*64*81          -> 14980096
constexpr size_t OFF_FEAT = 14980096;     // 512*3136           -> 16585728
// fcw split-K partials live in OFF_M0 (dead until the m0 GEMM runs)
// permuted m1w lives in the dead H1 region (dead after conv2, until upconv1
// overwrites R1 — by then gemm128 has consumed it)
constexpr size_t OFF_M1WT = OFF_H1;              // 10584*512 -> +5419008
constexpr size_t OFF_M1BT = OFF_H1 + 5419008;    // 10584     (< OFF_H2)

// ---- generic weight transpose: w[oc][ckk] -> wt[ckk][oc] ----
__global__ void transpose_w(const float* __restrict__ w, float* __restrict__ wt,
                            int OC, int CKK) {
  int idx = blockIdx.x * 256 + threadIdx.x;
  if (idx < OC * CKK) {
    int oc = idx / CKK, ckk = idx % CKK;
    wt[ckk * OC + oc] = w[idx];
  }
}

// ---- permute m1w rows so the m0 GEMM emits [b][y][x][c] directly ----
// n = c*441 + y*21 + x  ->  np = (y*21+x)*24 + c = (n%441)*24 + n/441
__global__ __launch_bounds__(128) void permute_m1(
    const float* __restrict__ m1w, const float* __restrict__ m1b,
    float* __restrict__ wT, float* __restrict__ bT) {
  const int n = blockIdx.x;              // 0..10583
  const int c = n / 441, rem = n % 441;
  const int np = rem * 24 + c;
  const float4* src = (const float4*)(m1w + (size_t)n * 512);
  float4* dst = (float4*)(wT + (size_t)np * 512);
  dst[threadIdx.x] = src[threadIdx.x];   // 128 * float4 = 512 floats
  if (threadIdx.x == 0) bT[np] = m1b[n];
}

// ---- conv1: [B,2,84,84] -> [B,32,20,20], k=8 s=4, relu. LDS 44.6 KB ----
__global__ __launch_bounds__(256) void conv1_k(
    const float* __restrict__ inp, const float* __restrict__ w,
    const float* __restrict__ bias, float* __restrict__ out) {
  __shared__ __align__(16) float sIn[NPIX];      // one channel at a time
  __shared__ __align__(16) float sW[128 * 32];   // [c][u][v][oc]
  const int b = blockIdx.x, t = threadIdx.x;
  for (int i = t; i < 4096; i += 256) {
    int oc = i >> 7, ckk = i & 127;
    sW[ckk * 32 + oc] = w[i];
  }
  const float* ip = inp + (size_t)b * 2 * NPIX;
  const int oc0 = (t & 7) * 4;
  const int pg  = t >> 3;
  int ibase[13];
#pragma unroll
  for (int k = 0; k < 13; k++) {
    int p = pg + 32 * k; if (p > 399) p = 399;
    ibase[k] = (p / 20) * 4 * 84 + (p % 20) * 4;
  }
  f32x2 acc[13][2];
#pragma unroll
  for (int k = 0; k < 13; k++) { acc[k][0] = f32x2{0.f, 0.f}; acc[k][1] = f32x2{0.f, 0.f}; }
  for (int c = 0; c < 2; c++) {
    __syncthreads();
    for (int i = t; i < NPIX; i += 256) sIn[i] = ip[c * NPIX + i];
    __syncthreads();
    for (int u = 0; u < 8; u++) {
#pragma unroll
      for (int v = 0; v < 8; v++) {
        const float4 wv = *(const float4*)&sW[((c * 8 + u) * 8 + v) * 32 + oc0];
        const f32x2 w0 = {wv.x, wv.y}, w1 = {wv.z, wv.w};
        const int off = u * 84 + v;
#pragma unroll
        for (int k = 0; k < 13; k++) {
          float x = sIn[off + ibase[k]];
          f32x2 xv = {x, x};
          acc[k][0] = pkfma(w0, xv, acc[k][0]);
          acc[k][1] = pkfma(w1, xv, acc[k][1]);
        }
      }
    }
  }
  float b0 = bias[oc0], b1 = bias[oc0+1], b2 = bias[oc0+2], b3 = bias[oc0+3];
  float* op = out + (size_t)b * 32 * 400;
#pragma unroll
  for (int k = 0; k < 13; k++) {
    int p = pg + 32 * k;
    if (p < 400) {
      op[(oc0+0)*400 + p] = fmaxf(acc[k][0][0] + b0, 0.f);
      op[(oc0+1)*400 + p] = fmaxf(acc[k][0][1] + b1, 0.f);
      op[(oc0+2)*400 + p] = fmaxf(acc[k][1][0] + b2, 0.f);
      op[(oc0+3)*400 + p] = fmaxf(acc[k][1][1] + b3, 0.f);
    }
  }
}

// ---- conv2: [B,32,20,20] -> [B,64,9,9], k=4 s=2, relu. LDS 51.2 KB ----
__global__ __launch_bounds__(256) void conv2_k(
    const float* __restrict__ in, const float* __restrict__ wt,
    const float* __restrict__ bias, float* __restrict__ out) {
  __shared__ float sIn[32 * 400];
  const int b = blockIdx.x, t = threadIdx.x;
  const float* ip = in + (size_t)b * 12800;
  for (int i = t; i < 12800; i += 256) sIn[i] = ip[i];
  __syncthreads();
  const int oc0 = (t & 7) * 8;
  const int pg  = t >> 3;
  int base[3];
#pragma unroll
  for (int k = 0; k < 3; k++) {
    int p = pg + 32 * k; if (p > 80) p = 80;
    base[k] = (p / 9) * 40 + (p % 9) * 2;
  }
  f32x2 acc[3][4];
#pragma unroll
  for (int k = 0; k < 3; k++)
#pragma unroll
    for (int o = 0; o < 4; o++) acc[k][o] = f32x2{0.f, 0.f};
  for (int c = 0; c < 32; c++) {
#pragma unroll
    for (int u = 0; u < 4; u++)
#pragma unroll
      for (int v = 0; v < 4; v++) {
        const float* wp = wt + ((c * 4 + u) * 4 + v) * 64 + oc0;
        float4 wa = *(const float4*)wp;
        float4 wb = *(const float4*)(wp + 4);
        const f32x2 w0 = {wa.x, wa.y}, w1 = {wa.z, wa.w};
        const f32x2 w2 = {wb.x, wb.y}, w3 = {wb.z, wb.w};
        int off = c * 400 + u * 20 + v;
#pragma unroll
        for (int k = 0; k < 3; k++) {
          float x = sIn[off + base[k]];
          f32x2 xv = {x, x};
          acc[k][0] = pkfma(w0, xv, acc[k][0]);
          acc[k][1] = pkfma(w1, xv, acc[k][1]);
          acc[k][2] = pkfma(w2, xv, acc[k][2]);
          acc[k][3] = pkfma(w3, xv, acc[k][3]);
        }
      }
  }
  float* op = out + (size_t)b * 5184;
#pragma unroll
  for (int k = 0; k < 3; k++) {
    int p = pg + 32 * k;
    if (p < 81) {
#pragma unroll
      for (int o = 0; o < 8; o++)
        op[(oc0+o)*81 + p] = fmaxf(acc[k][o >> 1][o & 1] + bias[oc0+o], 0.f);
    }
  }
}

// ---- conv3: [B,64,9,9] -> feat [B,3136] (= [64][7][7] flat), k=3 s=1, relu ----
__global__ __launch_bounds__(256) void conv3_k(
    const float* __restrict__ in, const float* __restrict__ wt,
    const float* __restrict__ bias, float* __restrict__ out) {
  __shared__ float sIn[64 * 81];
  const int b = blockIdx.x, t = threadIdx.x;
  const float* ip = in + (size_t)b * 5184;
  for (int i = t; i < 5184; i += 256) sIn[i] = ip[i];
  __syncthreads();
  const int oc0 = (t & 7) * 8;
  const int pg  = t >> 3;
  int base[2];
#pragma unroll
  for (int k = 0; k < 2; k++) {
    int p = pg + 32 * k; if (p > 48) p = 48;
    base[k] = (p / 7) * 9 + (p % 7);
  }
  f32x2 acc[2][4];
#pragma unroll
  for (int k = 0; k < 2; k++)
#pragma unroll
    for (int o = 0; o < 4; o++) acc[k][o] = f32x2{0.f, 0.f};
  for (int c = 0; c < 64; c++) {
#pragma unroll
    for (int u = 0; u < 3; u++)
#pragma unroll
      for (int v = 0; v < 3; v++) {
        const float* wp = wt + ((c * 3 + u) * 3 + v) * 64 + oc0;
        float4 wa = *(const float4*)wp;
        float4 wb = *(const float4*)(wp + 4);
        const f32x2 w0 = {wa.x, wa.y}, w1 = {wa.z, wa.w};
        const f32x2 w2 = {wb.x, wb.y}, w3 = {wb.z, wb.w};
        int off = c * 81 + u * 9 + v;
#pragma unroll
        for (int k = 0; k < 2; k++) {
          float x = sIn[off + base[k]];
          f32x2 xv = {x, x};
          acc[k][0] = pkfma(w0, xv, acc[k][0]);
          acc[k][1] = pkfma(w1, xv, acc[k][1]);
          acc[k][2] = pkfma(w2, xv, acc[k][2]);
          acc[k][3] = pkfma(w3, xv, acc[k][3]);
        }
      }
  }
  float* op = out + (size_t)b * 3136;
#pragma unroll
  for (int k = 0; k < 2; k++) {
    int p = pg + 32 * k;
    if (p < 49) {
#pragma unroll
      for (int o = 0; o < 8; o++)
        op[(oc0+o)*49 + p] = fmaxf(acc[k][o >> 1][o & 1] + bias[oc0+o], 0.f);
    }
  }
}

// ---- GEMM 64x64 tile: C[M,N] = A[M,K] @ W[N,K]^T + bias, optional relu ----
template<bool RELU>
__global__ __launch_bounds__(256) void gemm_k(
    const float* __restrict__ A, const float* __restrict__ Wm,
    const float* __restrict__ bias, float* __restrict__ C,
    int N, int K) {
  __shared__ __align__(16) float As[16][68];
  __shared__ __align__(16) float Ws[16][68];
  const int t = threadIdx.x;
  const int m0 = blockIdx.y * 64, n0 = blockIdx.x * 64;
  const int r  = t >> 2;
  const int kq = (t & 3) * 4;
  const int r0 = (t >> 4) * 4, c0 = (t & 15) * 4;
  f32x2 acc[4][2];
#pragma unroll
  for (int i = 0; i < 4; i++) { acc[i][0] = f32x2{0.f, 0.f}; acc[i][1] = f32x2{0.f, 0.f}; }
  for (int k0 = 0; k0 < K; k0 += 16) {
    float4 a = *(const float4*)(A + (size_t)(m0 + r) * K + k0 + kq);
    int wrow = n0 + r;
    float4 wv = make_float4(0.f, 0.f, 0.f, 0.f);
    if (wrow < N) wv = *(const float4*)(Wm + (size_t)wrow * K + k0 + kq);
    __syncthreads();
    As[kq+0][r] = a.x; As[kq+1][r] = a.y; As[kq+2][r] = a.z; As[kq+3][r] = a.w;
    Ws[kq+0][r] = wv.x; Ws[kq+1][r] = wv.y; Ws[kq+2][r] = wv.z; Ws[kq+3][r] = wv.w;
    __syncthreads();
#pragma unroll
    for (int kk = 0; kk < 16; kk++) {
      float4 av = *(const float4*)&As[kk][r0];
      float4 bv = *(const float4*)&Ws[kk][c0];
      const f32x2 b0 = {bv.x, bv.y}, b1 = {bv.z, bv.w};
      float ar[4] = {av.x, av.y, av.z, av.w};
#pragma unroll
      for (int i = 0; i < 4; i++) {
        f32x2 ai = {ar[i], ar[i]};
        acc[i][0] = pkfma(b0, ai, acc[i][0]);
        acc[i][1] = pkfma(b1, ai, acc[i][1]);
      }
    }
  }
#pragma unroll
  for (int i = 0; i < 4; i++) {
    int row = m0 + r0 + i;
#pragma unroll
    for (int j = 0; j < 4; j++) {
      int col = n0 + c0 + j;
      if (col < N) {
        float v = acc[i][j >> 1][j & 1] + bias[col];
        C[(size_t)row * N + col] = RELU ? fmaxf(v, 0.f) : v;
      }
    }
  }
}

// ---- split-K GEMM (no bias/relu): Cpart[z][M][N] partial over K-slice ----
__global__ __launch_bounds__(256) void gemm_splitk_k(
    const float* __restrict__ A, const float* __restrict__ Wm,
    float* __restrict__ Cpart, int N, int K, int Kslice) {
  __shared__ __align__(16) float As[16][68];
  __shared__ __align__(16) float Ws[16][68];
  const int t = threadIdx.x;
  const int m0 = blockIdx.y * 64, n0 = blockIdx.x * 64;
  const int kbeg = blockIdx.z * Kslice;
  const int kend = kbeg + Kslice;
  const int r  = t >> 2;
  const int kq = (t & 3) * 4;
  const int r0 = (t >> 4) * 4, c0 = (t & 15) * 4;
  f32x2 acc[4][2];
#pragma unroll
  for (int i = 0; i < 4; i++) { acc[i][0] = f32x2{0.f, 0.f}; acc[i][1] = f32x2{0.f, 0.f}; }
  for (int k0 = kbeg; k0 < kend; k0 += 16) {
    float4 a = *(const float4*)(A + (size_t)(m0 + r) * K + k0 + kq);
    float4 wv = *(const float4*)(Wm + (size_t)(n0 + r) * K + k0 + kq);
    __syncthreads();
    As[kq+0][r] = a.x; As[kq+1][r] = a.y; As[kq+2][r] = a.z; As[kq+3][r] = a.w;
    Ws[kq+0][r] = wv.x; Ws[kq+1][r] = wv.y; Ws[kq+2][r] = wv.z; Ws[kq+3][r] = wv.w;
    __syncthreads();
#pragma unroll
    for (int kk = 0; kk < 16; kk++) {
      float4 av = *(const float4*)&As[kk][r0];
      float4 bv = *(const float4*)&Ws[kk][c0];
      const f32x2 b0 = {bv.x, bv.y}, b1 = {bv.z, bv.w};
      float ar[4] = {av.x, av.y, av.z, av.w};
#pragma unroll
      for (int i = 0; i < 4; i++) {
        f32x2 ai = {ar[i], ar[i]};
        acc[i][0] = pkfma(b0, ai, acc[i][0]);
        acc[i][1] = pkfma(b1, ai, acc[i][1]);
      }
    }
  }
  float* cp = Cpart + (size_t)blockIdx.z * 512 * 512;
#pragma unroll
  for (int i = 0; i < 4; i++) {
    int row = m0 + r0 + i;
#pragma unroll
    for (int j = 0; j < 4; j++)
      cp[(size_t)row * N + n0 + c0 + j] = acc[i][j >> 1][j & 1];
  }
}

// ---- reduce 4 split-K partials + bias + relu -> X [512][512] ----
__global__ __launch_bounds__(256) void splitk_reduce_k(
    const float* __restrict__ Cpart, const float* __restrict__ bias,
    float* __restrict__ X) {
  int i4 = blockIdx.x * 256 + threadIdx.x;     // float4 index over 512*512/4
  if (i4 < 65536) {
    int col4 = (i4 & 127) * 4;
    float4 p0 = *(const float4*)&Cpart[(size_t)i4 * 4];
    float4 p1 = *(const float4*)&Cpart[262144 + (size_t)i4 * 4];
    float4 p2 = *(const float4*)&Cpart[524288 + (size_t)i4 * 4];
    float4 p3 = *(const float4*)&Cpart[786432 + (size_t)i4 * 4];
    float4 bb = *(const float4*)&bias[col4];
    float4 o;
    o.x = fmaxf(p0.x + p1.x + p2.x + p3.x + bb.x, 0.f);
    o.y = fmaxf(p0.y + p1.y + p2.y + p3.y + bb.y, 0.f);
    o.z = fmaxf(p0.z + p1.z + p2.z + p3.z + bb.z, 0.f);
    o.w = fmaxf(p0.w + p1.w + p2.w + p3.w + bb.w, 0.f);
    *(float4*)&X[(size_t)i4 * 4] = o;
  }
}

// ---- GEMM 128x128 tile, 8x8/thread (for large-N m0 matmul). No relu. ----
__global__ __launch_bounds__(256) void gemm128_k(
    const float* __restrict__ A, const float* __restrict__ Wm,
    const float* __restrict__ bias, float* __restrict__ C,
    int N, int K) {
  __shared__ __align__(16) float As[16][132];
  __shared__ __align__(16) float Ws[16][132];
  const int t = threadIdx.x;
  const int m0 = blockIdx.y * 128, n0 = blockIdx.x * 128;
  const int lr = t >> 1;            // 0..127 staging row
  const int kq = (t & 1) * 8;       // 0 or 8
  const int r0 = (t >> 4) * 8, c0 = (t & 15) * 8;
  f32x2 acc[8][4];
#pragma unroll
  for (int i = 0; i < 8; i++)
#pragma unroll
    for (int j = 0; j < 4; j++) acc[i][j] = f32x2{0.f, 0.f};
  for (int k0 = 0; k0 < K; k0 += 16) {
    const float* ap = A + (size_t)(m0 + lr) * K + k0 + kq;
    float4 a0 = *(const float4*)ap;
    float4 a1 = *(const float4*)(ap + 4);
    int wrow = n0 + lr;
    float4 w0 = make_float4(0.f,0.f,0.f,0.f), w1 = make_float4(0.f,0.f,0.f,0.f);
    if (wrow < N) {
      const float* wp = Wm + (size_t)wrow * K + k0 + kq;
      w0 = *(const float4*)wp;
      w1 = *(const float4*)(wp + 4);
    }
    __syncthreads();
    As[kq+0][lr] = a0.x; As[kq+1][lr] = a0.y; As[kq+2][lr] = a0.z; As[kq+3][lr] = a0.w;
    As[kq+4][lr] = a1.x; As[kq+5][lr] = a1.y; As[kq+6][lr] = a1.z; As[kq+7][lr] = a1.w;
    Ws[kq+0][lr] = w0.x; Ws[kq+1][lr] = w0.y; Ws[kq+2][lr] = w0.z; Ws[kq+3][lr] = w0.w;
    Ws[kq+4][lr] = w1.x; Ws[kq+5][lr] = w1.y; Ws[kq+6][lr] = w1.z; Ws[kq+7][lr] = w1.w;
    __syncthreads();
#pragma unroll
    for (int kk = 0; kk < 16; kk++) {
      float4 av0 = *(const float4*)&As[kk][r0];
      float4 av1 = *(const float4*)&As[kk][r0 + 4];
      float4 bv0 = *(const float4*)&Ws[kk][c0];
      float4 bv1 = *(const float4*)&Ws[kk][c0 + 4];
      float ar[8] = {av0.x, av0.y, av0.z, av0.w, av1.x, av1.y, av1.z, av1.w};
      f32x2 br[4] = {{bv0.x, bv0.y}, {bv0.z, bv0.w}, {bv1.x, bv1.y}, {bv1.z, bv1.w}};
#pragma unroll
      for (int i = 0; i < 8; i++) {
        f32x2 ai = {ar[i], ar[i]};
#pragma unroll
        for (int j = 0; j < 4; j++) acc[i][j] = pkfma(br[j], ai, acc[i][j]);
      }
    }
  }
#pragma unroll
  for (int i = 0; i < 8; i++) {
    int row = m0 + r0 + i;
#pragma unroll
    for (int j = 0; j < 8; j++) {
      int col = n0 + c0 + j;
      if (col < N)
        C[(size_t)row * N + col] = acc[i][j >> 1][j & 1] + bias[col];
    }
  }
}

// ---- upconv1: upsample 21->42 + residual 3x3 conv + relu.
//      Input M0 is channel-last [b][21][21][24]; fill loads 4 neighbor
//      pixels as 6xfloat4 each.  Conv unchanged ([ch][pos] LDS).  Output
//      R1T is channel-last [b][42][42][24] (6x dwordx4 stores). ----
__global__ __launch_bounds__(384, 6) void upconv1_k(
    const float* __restrict__ X, const float* __restrict__ wt,
    const float* __restrict__ bias, float* __restrict__ outT) {
  constexpr int S_IN = 21, S_OUT = 42, TR = 6, UH = 8, UW = 44, NTILE = 7;
  __shared__ __align__(16) float sU[24 * UH * UW];   // 8448 floats = 33 KB
  const int b = blockIdx.x / NTILE;
  const int y0 = (blockIdx.x % NTILE) * TR;
  const int t = threadIdx.x;
  const float* xb = X + (size_t)b * 24 * S_IN * S_IN;   // [21][21][24]
  const float sc = (float)(S_IN - 1) / (float)(S_OUT - 1);
  for (int rr = t; rr < UH * UW; rr += 384) {
    const int ry = rr / UW, cx = rr % UW;
    const int y = y0 + ry - 1, x = cx - 1;
    float* sdst = &sU[rr];
    if (y >= 0 && y < S_OUT && x >= 0 && x < S_OUT) {
      float py = y * sc, px = x * sc;
      int ly = (int)py; if (ly > S_IN - 2) ly = S_IN - 2;
      int lx = (int)px; if (lx > S_IN - 2) lx = S_IN - 2;
      float wy = py - (float)ly, wx = px - (float)lx;
      const f32x4 wx4 = {wx, wx, wx, wx};
      const f32x4 wy4 = {wy, wy, wy, wy};
      const float* p00 = xb + ((size_t)ly * S_IN + lx) * 24;
#pragma unroll
      for (int g = 0; g < 6; g++) {
        f32x4 q00 = *(const f32x4*)(p00 + 4 * g);
        f32x4 q01 = *(const f32x4*)(p00 + 24 + 4 * g);
        f32x4 q10 = *(const f32x4*)(p00 + 24 * S_IN + 4 * g);
        f32x4 q11 = *(const f32x4*)(p00 + 24 * S_IN + 24 + 4 * g);
        f32x4 ht = fma4(wx4, q01 - q00, q00);
        f32x4 hb = fma4(wx4, q11 - q10, q10);
        f32x4 v  = fma4(wy4, hb - ht, ht);
        sdst[(4*g + 0) * UH * UW] = v[0];
        sdst[(4*g + 1) * UH * UW] = v[1];
        sdst[(4*g + 2) * UH * UW] = v[2];
        sdst[(4*g + 3) * UH * UW] = v[3];
      }
    } else {
#pragma unroll
      for (int c = 0; c < 24; c++) sdst[c * UH * UW] = 0.f;
    }
  }
  __syncthreads();
  if (t < 252) {
    const int ry = t / 42, lx = t % 42;
    f32x2 acc[12];
#pragma unroll
    for (int j = 0; j < 12; j++) acc[j] = f32x2{0.f, 0.f};
    for (int ic = 0; ic < 24; ic++) {
      const float* urow = &sU[(ic * UH + ry) * UW + lx];
      const float* wp = wt + ic * 216;   // [3][3][24], uniform -> s_load
#pragma unroll
      for (int ky = 0; ky < 3; ky++) {
        float x0v = urow[ky * UW + 0];
        float x1v = urow[ky * UW + 1];
        float x2v = urow[ky * UW + 2];
        f32x2 X0 = {x0v, x0v}, X1 = {x1v, x1v}, X2 = {x2v, x2v};
        const f32x2* wk2 = (const f32x2*)(wp + ky * 72);
#pragma unroll
        for (int j = 0; j < 12; j++)
          acc[j] = pkfma(wk2[j], X0,
                   pkfma(wk2[12 + j], X1,
                   pkfma(wk2[24 + j], X2, acc[j])));
      }
    }
    const int yy = y0 + ry;
    float* orow = outT + ((size_t)b * 1764 + yy * 42 + lx) * 24;
#pragma unroll
    for (int g = 0; g < 6; g++) {
      f32x4 u = { sU[((4*g + 0) * UH + ry + 1) * UW + lx + 1],
                  sU[((4*g + 1) * UH + ry + 1) * UW + lx + 1],
                  sU[((4*g + 2) * UH + ry + 1) * UW + lx + 1],
                  sU[((4*g + 3) * UH + ry + 1) * UW + lx + 1] };
      f32x4 a = {acc[2*g][0], acc[2*g][1], acc[2*g+1][0], acc[2*g+1][1]};
      f32x4 bb = *(const f32x4*)&bias[4*g];
      f32x4 s = u + a + bb;
      s[0] = fmaxf(s[0], 0.f); s[1] = fmaxf(s[1], 0.f);
      s[2] = fmaxf(s[2], 0.f); s[3] = fmaxf(s[3], 0.f);
      *(f32x4*)(orow + 4*g) = s;
    }
  }
}

// ---- fused: upsample 42->84 + residual conv + relu + 1x1 conv + sigmoid
//      + flow + bilinear warp.  Input R1T channel-last [b][42][42][24];
//      fill via 4-neighbor float4 loads.  Conv/epilogue unchanged. ----
__global__ __launch_bounds__(384, 6) void upconv2_final_k(
    const float* __restrict__ R1T, const float* __restrict__ inp,
    const float* __restrict__ wt, const float* __restrict__ bias,
    const float* __restrict__ c3w, const float* __restrict__ c3b,
    const float* __restrict__ ot, const float* __restrict__ ct,
    float* __restrict__ out) {
  constexpr int S_IN = 42, S_OUT = 84, TR = 6, UH = 8, TW = 42, UW = 44;
  __shared__ __align__(16) float sU[24 * UH * UW];   // 8448 floats = 33 KB
  const int blk = blockIdx.x;
  const int b = blk / 28;
  const int rr0 = blk % 28;
  const int y0 = (rr0 >> 1) * TR;
  const int x0 = (rr0 & 1) * TW;
  const int t = threadIdx.x;
  const float* xb = R1T + (size_t)b * 1764 * 24;   // [42][42][24]
  const float sc = (float)(S_IN - 1) / (float)(S_OUT - 1);
  for (int rr = t; rr < UH * UW; rr += 384) {
    const int ry = rr / UW, cx = rr % UW;
    const int y = y0 + ry - 1, x = x0 + cx - 1;
    float* sdst = &sU[rr];
    if (y >= 0 && y < S_OUT && x >= 0 && x < S_OUT) {
      float py = y * sc, px = x * sc;
      int ly = (int)py; if (ly > S_IN - 2) ly = S_IN - 2;
      int lx = (int)px; if (lx > S_IN - 2) lx = S_IN - 2;
      float wy = py - (float)ly, wx = px - (float)lx;
      const f32x4 wx4 = {wx, wx, wx, wx};
      const f32x4 wy4 = {wy, wy, wy, wy};
      const float* p00 = xb + ((size_t)ly * S_IN + lx) * 24;
#pragma unroll
      for (int g = 0; g < 6; g++) {
        f32x4 q00 = *(const f32x4*)(p00 + 4 * g);
        f32x4 q01 = *(const f32x4*)(p00 + 24 + 4 * g);
        f32x4 q10 = *(const f32x4*)(p00 + 24 * S_IN + 4 * g);
        f32x4 q11 = *(const f32x4*)(p00 + 24 * S_IN + 24 + 4 * g);
        f32x4 ht = fma4(wx4, q01 - q00, q00);
        f32x4 hb = fma4(wx4, q11 - q10, q10);
        f32x4 v  = fma4(wy4, hb - ht, ht);
        sdst[(4*g + 0) * UH * UW] = v[0];
        sdst[(4*g + 1) * UH * UW] = v[1];
        sdst[(4*g + 2) * UH * UW] = v[2];
        sdst[(4*g + 3) * UH * UW] = v[3];
      }
    } else {
#pragma unroll
      for (int c = 0; c < 24; c++) sdst[c * UH * UW] = 0.f;
    }
  }
  __syncthreads();
  if (t < 252) {
    const int ry = t / 42, lx = t % 42;
    f32x2 acc[12];
#pragma unroll
    for (int j = 0; j < 12; j++) acc[j] = f32x2{0.f, 0.f};
    for (int ic = 0; ic < 24; ic++) {
      const float* urow = &sU[(ic * UH + ry) * UW + lx];
      const float* wp = wt + ic * 216;   // uniform -> s_load
#pragma unroll
      for (int ky = 0; ky < 3; ky++) {
        float x0v = urow[ky * UW + 0];
        float x1v = urow[ky * UW + 1];
        float x2v = urow[ky * UW + 2];
        f32x2 X0 = {x0v, x0v}, X1 = {x1v, x1v}, X2 = {x2v, x2v};
        const f32x2* wk2 = (const f32x2*)(wp + ky * 72);
#pragma unroll
        for (int j = 0; j < 12; j++)
          acc[j] = pkfma(wk2[j], X0,
                   pkfma(wk2[12 + j], X1,
                   pkfma(wk2[24 + j], X2, acc[j])));
      }
    }
    // residual + relu, kept in register pairs
    f32x2 r[12];
#pragma unroll
    for (int j = 0; j < 12; j++) {
      f32x2 u2 = { sU[((2*j)   * UH + ry + 1) * UW + lx + 1],
                   sU[((2*j+1) * UH + ry + 1) * UW + lx + 1] };
      f32x2 b2 = *(const f32x2*)&bias[2*j];
      f32x2 s = u2 + acc[j] + b2;
      r[j][0] = fmaxf(s[0], 0.f);
      r[j][1] = fmaxf(s[1], 0.f);
    }
    // 1x1 conv + sigmoid + flow accumulation (head params uniform -> SGPR)
    f32x2 f2 = *(const f32x2*)&ct[b * 2];            // {fy, fx}
    const f32x2* ot2 = (const f32x2*)(ot + b * 2 * KOBJ);
    for (int k = 0; k < KOBJ; k++) {
      f32x2 zv = {c3b[k], 0.f};
      const f32x2* cw2 = (const f32x2*)(c3w + k * 24);
#pragma unroll
      for (int j = 0; j < 12; j++) zv = pkfma(r[j], cw2[j], zv);
      float z = zv[0] + zv[1];
      float m = 1.f / (1.f + __expf(-z));
      f32x2 mv = {m, m};
      f2 = pkfma(mv, ot2[k], f2);
    }
    const int gy = y0 + ry, gx = x0 + lx;
    const float imgf = 0.01f * 84.0f;
    float ys = imgf * f2[0] + (float)gy;
    float xs = imgf * f2[1] + (float)gx;
    int ix0 = (int)floorf(xs); ix0 = ix0 < 0 ? 0 : (ix0 > 83 ? 83 : ix0);
    int iy0 = (int)floorf(ys); iy0 = iy0 < 0 ? 0 : (iy0 > 83 ? 83 : iy0);
    int ix1 = ix0 + 1 > 83 ? 83 : ix0 + 1;
    int iy1 = iy0 + 1 > 83 ? 83 : iy0 + 1;
    float xc = fminf(fmaxf(xs, 0.f), 83.f);
    float yc = fminf(fmaxf(ys, 0.f), 83.f);
    float wx1 = (float)ix1 - xc, wx0 = xc - (float)ix0;
    float wy1 = (float)iy1 - yc, wy0 = yc - (float)iy0;
    const float* src = inp + ((size_t)b * 2 + 1) * NPIX;
    float Ia = src[iy0 * 84 + ix0], Ib = src[iy1 * 84 + ix0];
    float Ic = src[iy0 * 84 + ix1], Id = src[iy1 * 84 + ix1];
    out[(size_t)b * NPIX + gy * 84 + gx] =
        wx1 * wy1 * Ia + wx1 * wy0 * Ib + wx0 * wy1 * Ic + wx0 * wy0 * Id;
  }
}

}  // namespace

extern "C" void kernel_launch(void* const* d_in, const int* in_sizes, int n_in,
                              void* d_out, int out_size, void* d_ws, size_t ws_size,
                              hipStream_t stream) {
  const float* inp = (const float*)d_in[0];
  const float* cw1 = (const float*)d_in[1];
  const float* cb1 = (const float*)d_in[2];
  const float* cw2 = (const float*)d_in[3];
  const float* cb2 = (const float*)d_in[4];
  const float* cw3 = (const float*)d_in[5];
  const float* cb3 = (const float*)d_in[6];
  const float* fcw = (const float*)d_in[7];
  const float* fcb = (const float*)d_in[8];
  const float* otw = (const float*)d_in[9];
  const float* otb = (const float*)d_in[10];
  const float* ctw = (const float*)d_in[11];
  const float* ctb = (const float*)d_in[12];
  const float* m1w = (const float*)d_in[13];
  const float* m1b = (const float*)d_in[14];
  const float* c1w = (const float*)d_in[15];
  const float* c1b = (const float*)d_in[16];
  const float* c2w = (const float*)d_in[17];
  const float* c2b = (const float*)d_in[18];
  const float* c3w = (const float*)d_in[19];
  const float* c3b = (const float*)d_in[20];
  float* W = (float*)d_ws;
  float* out = (float*)d_out;

  transpose_w<<<(64 * 512 + 255) / 256, 256, 0, stream>>>(cw2, W + OFF_WT2, 64, 512);
  transpose_w<<<(64 * 576 + 255) / 256, 256, 0, stream>>>(cw3, W + OFF_WT3, 64, 576);
  conv1_k<<<512, 256, 0, stream>>>(inp, cw1, cb1, W + OFF_H1);
  conv2_k<<<512, 256, 0, stream>>>(W + OFF_H1, W + OFF_WT2, cb2, W + OFF_H2);
  // H1 region dead now: build the permuted m1w/m1b there (consumed by gemm128)
  permute_m1<<<10584, 128, 0, stream>>>(m1w, m1b, W + OFF_M1WT, W + OFF_M1BT);
  conv3_k<<<512, 256, 0, stream>>>(W + OFF_H2, W + OFF_WT3, cb3, W + OFF_FEAT);
  // decoder conv weight transposes: [24][24][3][3] -> [ic*9+tap][oc]
  transpose_w<<<(24 * 216 + 255) / 256, 256, 0, stream>>>(c1w, W + OFF_WT2, 24, 216);
  transpose_w<<<(24 * 216 + 255) / 256, 256, 0, stream>>>(c2w, W + OFF_WT3, 24, 216);
  // x = relu(feat @ fcw^T + fcb)  -- split-K x4 (partials in dead OFF_M0)
  gemm_splitk_k<<<dim3(8, 8, 4), 256, 0, stream>>>(W + OFF_FEAT, fcw, W + OFF_M0,
                                                   512, 3136, 784);
  splitk_reduce_k<<<256, 256, 0, stream>>>(W + OFF_M0, fcb, W + OFF_X);
  // heads
  gemm_k<false><<<dim3(1, 8), 256, 0, stream>>>(W + OFF_X, otw, otb, W + OFF_OT, 40, 512);
  gemm_k<false><<<dim3(1, 8), 256, 0, stream>>>(W + OFF_X, ctw, ctb, W + OFF_CT, 2, 512);
  // m0 = x @ m1wT^T + m1bT  -> [b][21][21][24] channel-last directly
  gemm128_k<<<dim3(83, 4), 256, 0, stream>>>(W + OFF_X, W + OFF_M1WT, W + OFF_M1BT,
                                             W + OFF_M0, 10584, 512);
  // decoder (R1 stored channel-last [b][42][42][24])
  upconv1_k<<<512 * 7, 384, 0, stream>>>(W + OFF_M0, W + OFF_WT2, c1b, W + OFF_R1);
  upconv2_final_k<<<512 * 28, 384, 0, stream>>>(W + OFF_R1, inp, W + OFF_WT3, c2b,
                                                c3w, c3b, W + OFF_OT, W + OFF_CT, out);
}

// Round 8
// 1074.860 us; speedup vs baseline: 1.2413x; 1.0014x over previous
//
#include <hip/hip_runtime.h>
#include <math.h>

namespace {

typedef float f32x2 __attribute__((ext_vector_type(2)));
typedef float f32x4 __attribute__((ext_vector_type(4)));

#if defined(__has_builtin)
#if __has_builtin(__builtin_elementwise_fma)
#define HAVE_EW_FMA 1
#endif
#endif

__device__ __forceinline__ f32x2 pkfma(f32x2 a, f32x2 b, f32x2 c) {
#ifdef HAVE_EW_FMA
  return __builtin_elementwise_fma(a, b, c);
#else
  return a * b + c;
#endif
}
__device__ __forceinline__ f32x4 fma4(f32x4 a, f32x4 b, f32x4 c) {
#ifdef HAVE_EW_FMA
  return __builtin_elementwise_fma(a, b, c);
#else
  return a * b + c;
#endif
}

constexpr int IMS  = 84;
constexpr int NPIX = IMS * IMS;      // 7056
constexpr int KOBJ = 20;

// ---- workspace layout (float offsets), peak = 27448320 floats = 110 MB ----
constexpr size_t OFF_X    = 0;            // 512*512            -> 262144
constexpr size_t OFF_OT   = 262144;       // 512*40             -> 282624
constexpr size_t OFF_CT   = 282624;       // 512*2 (pad)        -> 283648
constexpr size_t OFF_WT2  = 283648;       // 512*64             -> 316416
constexpr size_t OFF_WT3  = 316416;       // 576*64             -> 353280
constexpr size_t OFF_M0   = 353280;       // 512*10584          -> 5772288
constexpr size_t OFF_R1   = 5772288;      // 512*24*42*42 (R1T) -> 27448320
// H1/H2/FEAT alias into the R1 region (dead before upconv1 writes R1)
constexpr size_t OFF_H1   = OFF_R1;       // 512*32*400         -> 12325888
constexpr size_t OFF_H2   = 12325888;     // 512*64*81          -> 14980096
constexpr size_t OFF_FEAT = 14980096;     // 512*3136           -> 16585728
// fcw split-K partials live in OFF_M0 (dead until the m0 GEMM runs)
// permuted m1w lives in the dead H1 region
constexpr size_t OFF_M1WT = OFF_H1;              // 10584*512 -> +5419008
constexpr size_t OFF_M1BT = OFF_H1 + 5419008;    // 10584     (< OFF_H2)

// ---- generic weight transpose: w[oc][ckk] -> wt[ckk][oc] ----
__global__ void transpose_w(const float* __restrict__ w, float* __restrict__ wt,
                            int OC, int CKK) {
  int idx = blockIdx.x * 256 + threadIdx.x;
  if (idx < OC * CKK) {
    int oc = idx / CKK, ckk = idx % CKK;
    wt[ckk * OC + oc] = w[idx];
  }
}

// ---- permute m1w rows so the m0 GEMM emits [b][y][x][c] directly ----
__global__ __launch_bounds__(128) void permute_m1(
    const float* __restrict__ m1w, const float* __restrict__ m1b,
    float* __restrict__ wT, float* __restrict__ bT) {
  const int n = blockIdx.x;              // 0..10583
  const int c = n / 441, rem = n % 441;
  const int np = rem * 24 + c;
  const float4* src = (const float4*)(m1w + (size_t)n * 512);
  float4* dst = (float4*)(wT + (size_t)np * 512);
  dst[threadIdx.x] = src[threadIdx.x];   // 128 * float4 = 512 floats
  if (threadIdx.x == 0) bT[np] = m1b[n];
}

// ---- conv1: [B,2,84,84] -> [B,32,20,20], k=8 s=4, relu. LDS 44.6 KB ----
__global__ __launch_bounds__(256) void conv1_k(
    const float* __restrict__ inp, const float* __restrict__ w,
    const float* __restrict__ bias, float* __restrict__ out) {
  __shared__ __align__(16) float sIn[NPIX];      // one channel at a time
  __shared__ __align__(16) float sW[128 * 32];   // [c][u][v][oc]
  const int b = blockIdx.x, t = threadIdx.x;
  for (int i = t; i < 4096; i += 256) {
    int oc = i >> 7, ckk = i & 127;
    sW[ckk * 32 + oc] = w[i];
  }
  const float* ip = inp + (size_t)b * 2 * NPIX;
  const int oc0 = (t & 7) * 4;
  const int pg  = t >> 3;
  int ibase[13];
#pragma unroll
  for (int k = 0; k < 13; k++) {
    int p = pg + 32 * k; if (p > 399) p = 399;
    ibase[k] = (p / 20) * 4 * 84 + (p % 20) * 4;
  }
  f32x2 acc[13][2];
#pragma unroll
  for (int k = 0; k < 13; k++) { acc[k][0] = f32x2{0.f, 0.f}; acc[k][1] = f32x2{0.f, 0.f}; }
  for (int c = 0; c < 2; c++) {
    __syncthreads();
    for (int i = t; i < NPIX; i += 256) sIn[i] = ip[c * NPIX + i];
    __syncthreads();
    for (int u = 0; u < 8; u++) {
#pragma unroll
      for (int v = 0; v < 8; v++) {
        const float4 wv = *(const float4*)&sW[((c * 8 + u) * 8 + v) * 32 + oc0];
        const f32x2 w0 = {wv.x, wv.y}, w1 = {wv.z, wv.w};
        const int off = u * 84 + v;
#pragma unroll
        for (int k = 0; k < 13; k++) {
          float x = sIn[off + ibase[k]];
          f32x2 xv = {x, x};
          acc[k][0] = pkfma(w0, xv, acc[k][0]);
          acc[k][1] = pkfma(w1, xv, acc[k][1]);
        }
      }
    }
  }
  float b0 = bias[oc0], b1 = bias[oc0+1], b2 = bias[oc0+2], b3 = bias[oc0+3];
  float* op = out + (size_t)b * 32 * 400;
#pragma unroll
  for (int k = 0; k < 13; k++) {
    int p = pg + 32 * k;
    if (p < 400) {
      op[(oc0+0)*400 + p] = fmaxf(acc[k][0][0] + b0, 0.f);
      op[(oc0+1)*400 + p] = fmaxf(acc[k][0][1] + b1, 0.f);
      op[(oc0+2)*400 + p] = fmaxf(acc[k][1][0] + b2, 0.f);
      op[(oc0+3)*400 + p] = fmaxf(acc[k][1][1] + b3, 0.f);
    }
  }
}

// ---- conv2: [B,32,20,20] -> [B,64,9,9], k=4 s=2, relu. LDS 51.2 KB ----
__global__ __launch_bounds__(256) void conv2_k(
    const float* __restrict__ in, const float* __restrict__ wt,
    const float* __restrict__ bias, float* __restrict__ out) {
  __shared__ float sIn[32 * 400];
  const int b = blockIdx.x, t = threadIdx.x;
  const float* ip = in + (size_t)b * 12800;
  for (int i = t; i < 12800; i += 256) sIn[i] = ip[i];
  __syncthreads();
  const int oc0 = (t & 7) * 8;
  const int pg  = t >> 3;
  int base[3];
#pragma unroll
  for (int k = 0; k < 3; k++) {
    int p = pg + 32 * k; if (p > 80) p = 80;
    base[k] = (p / 9) * 40 + (p % 9) * 2;
  }
  f32x2 acc[3][4];
#pragma unroll
  for (int k = 0; k < 3; k++)
#pragma unroll
    for (int o = 0; o < 4; o++) acc[k][o] = f32x2{0.f, 0.f};
  for (int c = 0; c < 32; c++) {
#pragma unroll
    for (int u = 0; u < 4; u++)
#pragma unroll
      for (int v = 0; v < 4; v++) {
        const float* wp = wt + ((c * 4 + u) * 4 + v) * 64 + oc0;
        float4 wa = *(const float4*)wp;
        float4 wb = *(const float4*)(wp + 4);
        const f32x2 w0 = {wa.x, wa.y}, w1 = {wa.z, wa.w};
        const f32x2 w2 = {wb.x, wb.y}, w3 = {wb.z, wb.w};
        int off = c * 400 + u * 20 + v;
#pragma unroll
        for (int k = 0; k < 3; k++) {
          float x = sIn[off + base[k]];
          f32x2 xv = {x, x};
          acc[k][0] = pkfma(w0, xv, acc[k][0]);
          acc[k][1] = pkfma(w1, xv, acc[k][1]);
          acc[k][2] = pkfma(w2, xv, acc[k][2]);
          acc[k][3] = pkfma(w3, xv, acc[k][3]);
        }
      }
  }
  float* op = out + (size_t)b * 5184;
#pragma unroll
  for (int k = 0; k < 3; k++) {
    int p = pg + 32 * k;
    if (p < 81) {
#pragma unroll
      for (int o = 0; o < 8; o++)
        op[(oc0+o)*81 + p] = fmaxf(acc[k][o >> 1][o & 1] + bias[oc0+o], 0.f);
    }
  }
}

// ---- conv3: [B,64,9,9] -> feat [B,3136] (= [64][7][7] flat), k=3 s=1, relu ----
__global__ __launch_bounds__(256) void conv3_k(
    const float* __restrict__ in, const float* __restrict__ wt,
    const float* __restrict__ bias, float* __restrict__ out) {
  __shared__ float sIn[64 * 81];
  const int b = blockIdx.x, t = threadIdx.x;
  const float* ip = in + (size_t)b * 5184;
  for (int i = t; i < 5184; i += 256) sIn[i] = ip[i];
  __syncthreads();
  const int oc0 = (t & 7) * 8;
  const int pg  = t >> 3;
  int base[2];
#pragma unroll
  for (int k = 0; k < 2; k++) {
    int p = pg + 32 * k; if (p > 48) p = 48;
    base[k] = (p / 7) * 9 + (p % 7);
  }
  f32x2 acc[2][4];
#pragma unroll
  for (int k = 0; k < 2; k++)
#pragma unroll
    for (int o = 0; o < 4; o++) acc[k][o] = f32x2{0.f, 0.f};
  for (int c = 0; c < 64; c++) {
#pragma unroll
    for (int u = 0; u < 3; u++)
#pragma unroll
      for (int v = 0; v < 3; v++) {
        const float* wp = wt + ((c * 3 + u) * 3 + v) * 64 + oc0;
        float4 wa = *(const float4*)wp;
        float4 wb = *(const float4*)(wp + 4);
        const f32x2 w0 = {wa.x, wa.y}, w1 = {wa.z, wa.w};
        const f32x2 w2 = {wb.x, wb.y}, w3 = {wb.z, wb.w};
        int off = c * 81 + u * 9 + v;
#pragma unroll
        for (int k = 0; k < 2; k++) {
          float x = sIn[off + base[k]];
          f32x2 xv = {x, x};
          acc[k][0] = pkfma(w0, xv, acc[k][0]);
          acc[k][1] = pkfma(w1, xv, acc[k][1]);
          acc[k][2] = pkfma(w2, xv, acc[k][2]);
          acc[k][3] = pkfma(w3, xv, acc[k][3]);
        }
      }
  }
  float* op = out + (size_t)b * 3136;
#pragma unroll
  for (int k = 0; k < 2; k++) {
    int p = pg + 32 * k;
    if (p < 49) {
#pragma unroll
      for (int o = 0; o < 8; o++)
        op[(oc0+o)*49 + p] = fmaxf(acc[k][o >> 1][o & 1] + bias[oc0+o], 0.f);
    }
  }
}

// ---- GEMM 64x64 tile: C[M,N] = A[M,K] @ W[N,K]^T + bias, optional relu ----
template<bool RELU>
__global__ __launch_bounds__(256) void gemm_k(
    const float* __restrict__ A, const float* __restrict__ Wm,
    const float* __restrict__ bias, float* __restrict__ C,
    int N, int K) {
  __shared__ __align__(16) float As[16][68];
  __shared__ __align__(16) float Ws[16][68];
  const int t = threadIdx.x;
  const int m0 = blockIdx.y * 64, n0 = blockIdx.x * 64;
  const int r  = t >> 2;
  const int kq = (t & 3) * 4;
  const int r0 = (t >> 4) * 4, c0 = (t & 15) * 4;
  f32x2 acc[4][2];
#pragma unroll
  for (int i = 0; i < 4; i++) { acc[i][0] = f32x2{0.f, 0.f}; acc[i][1] = f32x2{0.f, 0.f}; }
  for (int k0 = 0; k0 < K; k0 += 16) {
    float4 a = *(const float4*)(A + (size_t)(m0 + r) * K + k0 + kq);
    int wrow = n0 + r;
    float4 wv = make_float4(0.f, 0.f, 0.f, 0.f);
    if (wrow < N) wv = *(const float4*)(Wm + (size_t)wrow * K + k0 + kq);
    __syncthreads();
    As[kq+0][r] = a.x; As[kq+1][r] = a.y; As[kq+2][r] = a.z; As[kq+3][r] = a.w;
    Ws[kq+0][r] = wv.x; Ws[kq+1][r] = wv.y; Ws[kq+2][r] = wv.z; Ws[kq+3][r] = wv.w;
    __syncthreads();
#pragma unroll
    for (int kk = 0; kk < 16; kk++) {
      float4 av = *(const float4*)&As[kk][r0];
      float4 bv = *(const float4*)&Ws[kk][c0];
      const f32x2 b0 = {bv.x, bv.y}, b1 = {bv.z, bv.w};
      float ar[4] = {av.x, av.y, av.z, av.w};
#pragma unroll
      for (int i = 0; i < 4; i++) {
        f32x2 ai = {ar[i], ar[i]};
        acc[i][0] = pkfma(b0, ai, acc[i][0]);
        acc[i][1] = pkfma(b1, ai, acc[i][1]);
      }
    }
  }
#pragma unroll
  for (int i = 0; i < 4; i++) {
    int row = m0 + r0 + i;
#pragma unroll
    for (int j = 0; j < 4; j++) {
      int col = n0 + c0 + j;
      if (col < N) {
        float v = acc[i][j >> 1][j & 1] + bias[col];
        C[(size_t)row * N + col] = RELU ? fmaxf(v, 0.f) : v;
      }
    }
  }
}

// ---- split-K GEMM (no bias/relu): Cpart[z][M][N] partial over K-slice ----
__global__ __launch_bounds__(256) void gemm_splitk_k(
    const float* __restrict__ A, const float* __restrict__ Wm,
    float* __restrict__ Cpart, int N, int K, int Kslice) {
  __shared__ __align__(16) float As[16][68];
  __shared__ __align__(16) float Ws[16][68];
  const int t = threadIdx.x;
  const int m0 = blockIdx.y * 64, n0 = blockIdx.x * 64;
  const int kbeg = blockIdx.z * Kslice;
  const int kend = kbeg + Kslice;
  const int r  = t >> 2;
  const int kq = (t & 3) * 4;
  const int r0 = (t >> 4) * 4, c0 = (t & 15) * 4;
  f32x2 acc[4][2];
#pragma unroll
  for (int i = 0; i < 4; i++) { acc[i][0] = f32x2{0.f, 0.f}; acc[i][1] = f32x2{0.f, 0.f}; }
  for (int k0 = kbeg; k0 < kend; k0 += 16) {
    float4 a = *(const float4*)(A + (size_t)(m0 + r) * K + k0 + kq);
    float4 wv = *(const float4*)(Wm + (size_t)(n0 + r) * K + k0 + kq);
    __syncthreads();
    As[kq+0][r] = a.x; As[kq+1][r] = a.y; As[kq+2][r] = a.z; As[kq+3][r] = a.w;
    Ws[kq+0][r] = wv.x; Ws[kq+1][r] = wv.y; Ws[kq+2][r] = wv.z; Ws[kq+3][r] = wv.w;
    __syncthreads();
#pragma unroll
    for (int kk = 0; kk < 16; kk++) {
      float4 av = *(const float4*)&As[kk][r0];
      float4 bv = *(const float4*)&Ws[kk][c0];
      const f32x2 b0 = {bv.x, bv.y}, b1 = {bv.z, bv.w};
      float ar[4] = {av.x, av.y, av.z, av.w};
#pragma unroll
      for (int i = 0; i < 4; i++) {
        f32x2 ai = {ar[i], ar[i]};
        acc[i][0] = pkfma(b0, ai, acc[i][0]);
        acc[i][1] = pkfma(b1, ai, acc[i][1]);
      }
    }
  }
  float* cp = Cpart + (size_t)blockIdx.z * 512 * 512;
#pragma unroll
  for (int i = 0; i < 4; i++) {
    int row = m0 + r0 + i;
#pragma unroll
    for (int j = 0; j < 4; j++)
      cp[(size_t)row * N + n0 + c0 + j] = acc[i][j >> 1][j & 1];
  }
}

// ---- reduce 4 split-K partials + bias + relu -> X [512][512] ----
__global__ __launch_bounds__(256) void splitk_reduce_k(
    const float* __restrict__ Cpart, const float* __restrict__ bias,
    float* __restrict__ X) {
  int i4 = blockIdx.x * 256 + threadIdx.x;     // float4 index over 512*512/4
  if (i4 < 65536) {
    int col4 = (i4 & 127) * 4;
    float4 p0 = *(const float4*)&Cpart[(size_t)i4 * 4];
    float4 p1 = *(const float4*)&Cpart[262144 + (size_t)i4 * 4];
    float4 p2 = *(const float4*)&Cpart[524288 + (size_t)i4 * 4];
    float4 p3 = *(const float4*)&Cpart[786432 + (size_t)i4 * 4];
    float4 bb = *(const float4*)&bias[col4];
    float4 o;
    o.x = fmaxf(p0.x + p1.x + p2.x + p3.x + bb.x, 0.f);
    o.y = fmaxf(p0.y + p1.y + p2.y + p3.y + bb.y, 0.f);
    o.z = fmaxf(p0.z + p1.z + p2.z + p3.z + bb.z, 0.f);
    o.w = fmaxf(p0.w + p1.w + p2.w + p3.w + bb.w, 0.f);
    *(float4*)&X[(size_t)i4 * 4] = o;
  }
}

// ---- GEMM 128x128 tile, 8x8/thread (for large-N m0 matmul). No relu. ----
__global__ __launch_bounds__(256) void gemm128_k(
    const float* __restrict__ A, const float* __restrict__ Wm,
    const float* __restrict__ bias, float* __restrict__ C,
    int N, int K) {
  __shared__ __align__(16) float As[16][132];
  __shared__ __align__(16) float Ws[16][132];
  const int t = threadIdx.x;
  const int m0 = blockIdx.y * 128, n0 = blockIdx.x * 128;
  const int lr = t >> 1;            // 0..127 staging row
  const int kq = (t & 1) * 8;       // 0 or 8
  const int r0 = (t >> 4) * 8, c0 = (t & 15) * 8;
  f32x2 acc[8][4];
#pragma unroll
  for (int i = 0; i < 8; i++)
#pragma unroll
    for (int j = 0; j < 4; j++) acc[i][j] = f32x2{0.f, 0.f};
  for (int k0 = 0; k0 < K; k0 += 16) {
    const float* ap = A + (size_t)(m0 + lr) * K + k0 + kq;
    float4 a0 = *(const float4*)ap;
    float4 a1 = *(const float4*)(ap + 4);
    int wrow = n0 + lr;
    float4 w0 = make_float4(0.f,0.f,0.f,0.f), w1 = make_float4(0.f,0.f,0.f,0.f);
    if (wrow < N) {
      const float* wp = Wm + (size_t)wrow * K + k0 + kq;
      w0 = *(const float4*)wp;
      w1 = *(const float4*)(wp + 4);
    }
    __syncthreads();
    As[kq+0][lr] = a0.x; As[kq+1][lr] = a0.y; As[kq+2][lr] = a0.z; As[kq+3][lr] = a0.w;
    As[kq+4][lr] = a1.x; As[kq+5][lr] = a1.y; As[kq+6][lr] = a1.z; As[kq+7][lr] = a1.w;
    Ws[kq+0][lr] = w0.x; Ws[kq+1][lr] = w0.y; Ws[kq+2][lr] = w0.z; Ws[kq+3][lr] = w0.w;
    Ws[kq+4][lr] = w1.x; Ws[kq+5][lr] = w1.y; Ws[kq+6][lr] = w1.z; Ws[kq+7][lr] = w1.w;
    __syncthreads();
#pragma unroll
    for (int kk = 0; kk < 16; kk++) {
      float4 av0 = *(const float4*)&As[kk][r0];
      float4 av1 = *(const float4*)&As[kk][r0 + 4];
      float4 bv0 = *(const float4*)&Ws[kk][c0];
      float4 bv1 = *(const float4*)&Ws[kk][c0 + 4];
      float ar[8] = {av0.x, av0.y, av0.z, av0.w, av1.x, av1.y, av1.z, av1.w};
      f32x2 br[4] = {{bv0.x, bv0.y}, {bv0.z, bv0.w}, {bv1.x, bv1.y}, {bv1.z, bv1.w}};
#pragma unroll
      for (int i = 0; i < 8; i++) {
        f32x2 ai = {ar[i], ar[i]};
#pragma unroll
        for (int j = 0; j < 4; j++) acc[i][j] = pkfma(br[j], ai, acc[i][j]);
      }
    }
  }
#pragma unroll
  for (int i = 0; i < 8; i++) {
    int row = m0 + r0 + i;
#pragma unroll
    for (int j = 0; j < 8; j++) {
      int col = n0 + c0 + j;
      if (col < N)
        C[(size_t)row * N + col] = acc[i][j >> 1][j & 1] + bias[col];
    }
  }
}

// ---- upconv1: upsample 21->42 + residual 3x3 conv + relu.
//      Conv phase under a WAVE-UNIFORM branch (readfirstlane) so uniform
//      weight addresses scalarize to s_load; lanes 252-255 duplicate pixel
//      251 (LDS broadcast) and are store-masked. ----
__global__ __launch_bounds__(384, 6) void upconv1_k(
    const float* __restrict__ X, const float* __restrict__ wt,
    const float* __restrict__ bias, float* __restrict__ outT) {
  constexpr int S_IN = 21, S_OUT = 42, TR = 6, UH = 8, UW = 44, NTILE = 7;
  __shared__ __align__(16) float sU[24 * UH * UW];   // 8448 floats = 33 KB
  const int b = blockIdx.x / NTILE;
  const int y0 = (blockIdx.x % NTILE) * TR;
  const int t = threadIdx.x;
  const float* xb = X + (size_t)b * 24 * S_IN * S_IN;   // [21][21][24]
  const float sc = (float)(S_IN - 1) / (float)(S_OUT - 1);
  for (int rr = t; rr < UH * UW; rr += 384) {
    const int ry = rr / UW, cx = rr % UW;
    const int y = y0 + ry - 1, x = cx - 1;
    float* sdst = &sU[rr];
    if (y >= 0 && y < S_OUT && x >= 0 && x < S_OUT) {
      float py = y * sc, px = x * sc;
      int ly = (int)py; if (ly > S_IN - 2) ly = S_IN - 2;
      int lx = (int)px; if (lx > S_IN - 2) lx = S_IN - 2;
      float wy = py - (float)ly, wx = px - (float)lx;
      const f32x4 wx4 = {wx, wx, wx, wx};
      const f32x4 wy4 = {wy, wy, wy, wy};
      const float* p00 = xb + ((size_t)ly * S_IN + lx) * 24;
#pragma unroll
      for (int g = 0; g < 6; g++) {
        f32x4 q00 = *(const f32x4*)(p00 + 4 * g);
        f32x4 q01 = *(const f32x4*)(p00 + 24 + 4 * g);
        f32x4 q10 = *(const f32x4*)(p00 + 24 * S_IN + 4 * g);
        f32x4 q11 = *(const f32x4*)(p00 + 24 * S_IN + 24 + 4 * g);
        f32x4 ht = fma4(wx4, q01 - q00, q00);
        f32x4 hb = fma4(wx4, q11 - q10, q10);
        f32x4 v  = fma4(wy4, hb - ht, ht);
        sdst[(4*g + 0) * UH * UW] = v[0];
        sdst[(4*g + 1) * UH * UW] = v[1];
        sdst[(4*g + 2) * UH * UW] = v[2];
        sdst[(4*g + 3) * UH * UW] = v[3];
      }
    } else {
#pragma unroll
      for (int c = 0; c < 24; c++) sdst[c * UH * UW] = 0.f;
    }
  }
  __syncthreads();
  const int wid = __builtin_amdgcn_readfirstlane(t >> 6);   // uniform wave id
  if (wid < 4) {           // s_cbranch: waves 0-3, no lane divergence
    const int tp = t < 252 ? t : 251;   // dup lanes -> pixel 251 (broadcast)
    const int ry = tp / 42, lx = tp % 42;
    f32x2 acc[12];
#pragma unroll
    for (int j = 0; j < 12; j++) acc[j] = f32x2{0.f, 0.f};
    for (int ic = 0; ic < 24; ic++) {
      const float* urow = &sU[(ic * UH + ry) * UW + lx];
      const float* wp = wt + ic * 216;   // uniform addr in uniform CF -> s_load
#pragma unroll
      for (int ky = 0; ky < 3; ky++) {
        float x0v = urow[ky * UW + 0];
        float x1v = urow[ky * UW + 1];
        float x2v = urow[ky * UW + 2];
        f32x2 X0 = {x0v, x0v}, X1 = {x1v, x1v}, X2 = {x2v, x2v};
        const f32x2* wk2 = (const f32x2*)(wp + ky * 72);
#pragma unroll
        for (int j = 0; j < 12; j++)
          acc[j] = pkfma(wk2[j], X0,
                   pkfma(wk2[12 + j], X1,
                   pkfma(wk2[24 + j], X2, acc[j])));
      }
    }
    if (t < 252) {
      const int yy = y0 + ry;
      float* orow = outT + ((size_t)b * 1764 + yy * 42 + lx) * 24;
#pragma unroll
      for (int g = 0; g < 6; g++) {
        f32x4 u = { sU[((4*g + 0) * UH + ry + 1) * UW + lx + 1],
                    sU[((4*g + 1) * UH + ry + 1) * UW + lx + 1],
                    sU[((4*g + 2) * UH + ry + 1) * UW + lx + 1],
                    sU[((4*g + 3) * UH + ry + 1) * UW + lx + 1] };
        f32x4 a = {acc[2*g][0], acc[2*g][1], acc[2*g+1][0], acc[2*g+1][1]};
        f32x4 bb = *(const f32x4*)&bias[4*g];
        f32x4 s = u + a + bb;
        s[0] = fmaxf(s[0], 0.f); s[1] = fmaxf(s[1], 0.f);
        s[2] = fmaxf(s[2], 0.f); s[3] = fmaxf(s[3], 0.f);
        *(f32x4*)(orow + 4*g) = s;
      }
    }
  }
}

// ---- fused: upsample 42->84 + residual conv + relu + 1x1 conv + sigmoid
//      + flow + bilinear warp.  Same wave-uniform conv-phase branch. ----
__global__ __launch_bounds__(384, 6) void upconv2_final_k(
    const float* __restrict__ R1T, const float* __restrict__ inp,
    const float* __restrict__ wt, const float* __restrict__ bias,
    const float* __restrict__ c3w, const float* __restrict__ c3b,
    const float* __restrict__ ot, const float* __restrict__ ct,
    float* __restrict__ out) {
  constexpr int S_IN = 42, S_OUT = 84, TR = 6, UH = 8, TW = 42, UW = 44;
  __shared__ __align__(16) float sU[24 * UH * UW];   // 8448 floats = 33 KB
  const int blk = blockIdx.x;
  const int b = blk / 28;
  const int rr0 = blk % 28;
  const int y0 = (rr0 >> 1) * TR;
  const int x0 = (rr0 & 1) * TW;
  const int t = threadIdx.x;
  const float* xb = R1T + (size_t)b * 1764 * 24;   // [42][42][24]
  const float sc = (float)(S_IN - 1) / (float)(S_OUT - 1);
  for (int rr = t; rr < UH * UW; rr += 384) {
    const int ry = rr / UW, cx = rr % UW;
    const int y = y0 + ry - 1, x = x0 + cx - 1;
    float* sdst = &sU[rr];
    if (y >= 0 && y < S_OUT && x >= 0 && x < S_OUT) {
      float py = y * sc, px = x * sc;
      int ly = (int)py; if (ly > S_IN - 2) ly = S_IN - 2;
      int lx = (int)px; if (lx > S_IN - 2) lx = S_IN - 2;
      float wy = py - (float)ly, wx = px - (float)lx;
      const f32x4 wx4 = {wx, wx, wx, wx};
      const f32x4 wy4 = {wy, wy, wy, wy};
      const float* p00 = xb + ((size_t)ly * S_IN + lx) * 24;
#pragma unroll
      for (int g = 0; g < 6; g++) {
        f32x4 q00 = *(const f32x4*)(p00 + 4 * g);
        f32x4 q01 = *(const f32x4*)(p00 + 24 + 4 * g);
        f32x4 q10 = *(const f32x4*)(p00 + 24 * S_IN + 4 * g);
        f32x4 q11 = *(const f32x4*)(p00 + 24 * S_IN + 24 + 4 * g);
        f32x4 ht = fma4(wx4, q01 - q00, q00);
        f32x4 hb = fma4(wx4, q11 - q10, q10);
        f32x4 v  = fma4(wy4, hb - ht, ht);
        sdst[(4*g + 0) * UH * UW] = v[0];
        sdst[(4*g + 1) * UH * UW] = v[1];
        sdst[(4*g + 2) * UH * UW] = v[2];
        sdst[(4*g + 3) * UH * UW] = v[3];
      }
    } else {
#pragma unroll
      for (int c = 0; c < 24; c++) sdst[c * UH * UW] = 0.f;
    }
  }
  __syncthreads();
  const int wid = __builtin_amdgcn_readfirstlane(t >> 6);   // uniform wave id
  if (wid < 4) {           // s_cbranch: waves 0-3, no lane divergence
    const int tp = t < 252 ? t : 251;   // dup lanes -> pixel 251 (broadcast)
    const int ry = tp / 42, lx = tp % 42;
    f32x2 acc[12];
#pragma unroll
    for (int j = 0; j < 12; j++) acc[j] = f32x2{0.f, 0.f};
    for (int ic = 0; ic < 24; ic++) {
      const float* urow = &sU[(ic * UH + ry) * UW + lx];
      const float* wp = wt + ic * 216;   // uniform addr in uniform CF -> s_load
#pragma unroll
      for (int ky = 0; ky < 3; ky++) {
        float x0v = urow[ky * UW + 0];
        float x1v = urow[ky * UW + 1];
        float x2v = urow[ky * UW + 2];
        f32x2 X0 = {x0v, x0v}, X1 = {x1v, x1v}, X2 = {x2v, x2v};
        const f32x2* wk2 = (const f32x2*)(wp + ky * 72);
#pragma unroll
        for (int j = 0; j < 12; j++)
          acc[j] = pkfma(wk2[j], X0,
                   pkfma(wk2[12 + j], X1,
                   pkfma(wk2[24 + j], X2, acc[j])));
      }
    }
    // residual + relu, kept in register pairs
    f32x2 r[12];
#pragma unroll
    for (int j = 0; j < 12; j++) {
      f32x2 u2 = { sU[((2*j)   * UH + ry + 1) * UW + lx + 1],
                   sU[((2*j+1) * UH + ry + 1) * UW + lx + 1] };
      f32x2 b2 = *(const f32x2*)&bias[2*j];
      f32x2 s = u2 + acc[j] + b2;
      r[j][0] = fmaxf(s[0], 0.f);
      r[j][1] = fmaxf(s[1], 0.f);
    }
    // 1x1 conv + sigmoid + flow accumulation (head params uniform -> s_load)
    f32x2 f2 = *(const f32x2*)&ct[b * 2];            // {fy, fx}
    const f32x2* ot2 = (const f32x2*)(ot + b * 2 * KOBJ);
    for (int k = 0; k < KOBJ; k++) {
      f32x2 zv = {c3b[k], 0.f};
      const f32x2* cw2 = (const f32x2*)(c3w + k * 24);
#pragma unroll
      for (int j = 0; j < 12; j++) zv = pkfma(r[j], cw2[j], zv);
      float z = zv[0] + zv[1];
      float m = 1.f / (1.f + __expf(-z));
      f32x2 mv = {m, m};
      f2 = pkfma(mv, ot2[k], f2);
    }
    if (t < 252) {
      const int gy = y0 + ry, gx = x0 + lx;
      const float imgf = 0.01f * 84.0f;
      float ys = imgf * f2[0] + (float)gy;
      float xs = imgf * f2[1] + (float)gx;
      int ix0 = (int)floorf(xs); ix0 = ix0 < 0 ? 0 : (ix0 > 83 ? 83 : ix0);
      int iy0 = (int)floorf(ys); iy0 = iy0 < 0 ? 0 : (iy0 > 83 ? 83 : iy0);
      int ix1 = ix0 + 1 > 83 ? 83 : ix0 + 1;
      int iy1 = iy0 + 1 > 83 ? 83 : iy0 + 1;
      float xc = fminf(fmaxf(xs, 0.f), 83.f);
      float yc = fminf(fmaxf(ys, 0.f), 83.f);
      float wx1 = (float)ix1 - xc, wx0 = xc - (float)ix0;
      float wy1 = (float)iy1 - yc, wy0 = yc - (float)iy0;
      const float* src = inp + ((size_t)b * 2 + 1) * NPIX;
      float Ia = src[iy0 * 84 + ix0], Ib = src[iy1 * 84 + ix0];
      float Ic = src[iy0 * 84 + ix1], Id = src[iy1 * 84 + ix1];
      out[(size_t)b * NPIX + gy * 84 + gx] =
          wx1 * wy1 * Ia + wx1 * wy0 * Ib + wx0 * wy1 * Ic + wx0 * wy0 * Id;
    }
  }
}

}  // namespace

extern "C" void kernel_launch(void* const* d_in, const int* in_sizes, int n_in,
                              void* d_out, int out_size, void* d_ws, size_t ws_size,
                              hipStream_t stream) {
  const float* inp = (const float*)d_in[0];
  const float* cw1 = (const float*)d_in[1];
  const float* cb1 = (const float*)d_in[2];
  const float* cw2 = (const float*)d_in[3];
  const float* cb2 = (const float*)d_in[4];
  const float* cw3 = (const float*)d_in[5];
  const float* cb3 = (const float*)d_in[6];
  const float* fcw = (const float*)d_in[7];
  const float* fcb = (const float*)d_in[8];
  const float* otw = (const float*)d_in[9];
  const float* otb = (const float*)d_in[10];
  const float* ctw = (const float*)d_in[11];
  const float* ctb = (const float*)d_in[12];
  const float* m1w = (const float*)d_in[13];
  const float* m1b = (const float*)d_in[14];
  const float* c1w = (const float*)d_in[15];
  const float* c1b = (const float*)d_in[16];
  const float* c2w = (const float*)d_in[17];
  const float* c2b = (const float*)d_in[18];
  const float* c3w = (const float*)d_in[19];
  const float* c3b = (const float*)d_in[20];
  float* W = (float*)d_ws;
  float* out = (float*)d_out;

  transpose_w<<<(64 * 512 + 255) / 256, 256, 0, stream>>>(cw2, W + OFF_WT2, 64, 512);
  transpose_w<<<(64 * 576 + 255) / 256, 256, 0, stream>>>(cw3, W + OFF_WT3, 64, 576);
  conv1_k<<<512, 256, 0, stream>>>(inp, cw1, cb1, W + OFF_H1);
  conv2_k<<<512, 256, 0, stream>>>(W + OFF_H1, W + OFF_WT2, cb2, W + OFF_H2);
  // H1 region dead now: build the permuted m1w/m1b there (consumed by gemm128)
  permute_m1<<<10584, 128, 0, stream>>>(m1w, m1b, W + OFF_M1WT, W + OFF_M1BT);
  conv3_k<<<512, 256, 0, stream>>>(W + OFF_H2, W + OFF_WT3, cb3, W + OFF_FEAT);
  // decoder conv weight transposes: [24][24][3][3] -> [ic*9+tap][oc]
  transpose_w<<<(24 * 216 + 255) / 256, 256, 0, stream>>>(c1w, W + OFF_WT2, 24, 216);
  transpose_w<<<(24 * 216 + 255) / 256, 256, 0, stream>>>(c2w, W + OFF_WT3, 24, 216);
  // x = relu(feat @ fcw^T + fcb)  -- split-K x4 (partials in dead OFF_M0)
  gemm_splitk_k<<<dim3(8, 8, 4), 256, 0, stream>>>(W + OFF_FEAT, fcw, W + OFF_M0,
                                                   512, 3136, 784);
  splitk_reduce_k<<<256, 256, 0, stream>>>(W + OFF_M0, fcb, W + OFF_X);
  // heads
  gemm_k<false><<<dim3(1, 8), 256, 0, stream>>>(W + OFF_X, otw, otb, W + OFF_OT, 40, 512);
  gemm_k<false><<<dim3(1, 8), 256, 0, stream>>>(W + OFF_X, ctw, ctb, W + OFF_CT, 2, 512);
  // m0 = x @ m1wT^T + m1bT  -> [b][21][21][24] channel-last directly
  gemm128_k<<<dim3(83, 4), 256, 0, stream>>>(W + OFF_X, W + OFF_M1WT, W + OFF_M1BT,
                                             W + OFF_M0, 10584, 512);
  // decoder (R1 stored channel-last [b][42][42][24])
  upconv1_k<<<512 * 7, 384, 0, stream>>>(W + OFF_M0, W + OFF_WT2, c1b, W + OFF_R1);
  upconv2_final_k<<<512 * 28, 384, 0, stream>>>(W + OFF_R1, inp, W + OFF_WT3, c2b,
                                                c3w, c3b, W + OFF_OT, W + OFF_CT, out);
}